// Round 18
// baseline (125.748 us; speedup 1.0000x reference)
//
#include <hip/hip_runtime.h>
#include <hip/hip_bf16.h>
#include <stdint.h>

typedef __bf16 bf16;
typedef bf16 bf16x8 __attribute__((ext_vector_type(8)));
typedef float f32x4 __attribute__((ext_vector_type(4)));

#define NB   4
#define SS   2048
#define DI   1024
#define DOUT 1024

__device__ __forceinline__ void gload_lds16(const void* g, void* l) {
  __builtin_amdgcn_global_load_lds(
      (const __attribute__((address_space(1))) void*)g,
      (__attribute__((address_space(3))) void*)l, 16, 0, 0);
}

#define BARX  { __builtin_amdgcn_s_barrier(); __builtin_amdgcn_sched_barrier(0); }
#define VMW12 asm volatile("s_waitcnt vmcnt(12)" ::: "memory")
#define VMW8  asm volatile("s_waitcnt vmcnt(8)"  ::: "memory")
#define VMW6  asm volatile("s_waitcnt vmcnt(6)"  ::: "memory")
#define VMW4  asm volatile("s_waitcnt vmcnt(4)"  ::: "memory")
#define VMW3  asm volatile("s_waitcnt vmcnt(3)"  ::: "memory")
#define VMW0  asm volatile("s_waitcnt vmcnt(0)"  ::: "memory")

__device__ __forceinline__ bf16x8 cvt8(float4 a, float4 b) {
  bf16x8 v;
  v[0] = (bf16)a.x; v[1] = (bf16)a.y; v[2] = (bf16)a.z; v[3] = (bf16)a.w;
  v[4] = (bf16)b.x; v[5] = (bf16)b.y; v[6] = (bf16)b.z; v[7] = (bf16)b.w;
  return v;
}

// ------- r5_3: 128x256 tile, BK=32, TRIPLE-buffer (24KB x3), depth-2 --------
// 6 loads/tile -> 18 in flight; vmcnt(12) retires tile t.
// acc[am][fn]: row = m0 + am*16 + (lane>>4)*4 + r; col = n0 + w*64 + fn*16 + (lane&15)
// Conflict-free 64B-row LDS layout (r16 lesson: 128B-row linear = 16-way
// bank conflict, 9.4M/dispatch; this layout measures 0).
__device__ __forceinline__ void r5_loop3(
    const bf16* __restrict__ Ag, int lda,
    const bf16* __restrict__ Bg, int ldb,
    int nt, char* lds, f32x4 (&acc)[8][4])
{
  const int tid = threadIdx.x, lane = tid & 63, w = tid >> 6;
  const int g    = (tid & 3) ^ ((tid >> 3) & 3);
  const int srow = tid >> 2;
  const int l15  = lane & 15, lg = lane >> 4;
  const int aoff = l15 * 64 + ((lg ^ ((l15 >> 1) & 3)) << 4);

  auto STG = [&](int t, int p) {
    char* Ab = lds + p * 24576;
    char* Bb = lds + p * 24576 + 8192;
#pragma unroll
    for (int i = 0; i < 2; ++i)
      gload_lds16(Ag + (size_t)(i * 64 + srow) * lda + t * 32 + g * 8,
                  Ab + i * 4096 + tid * 16);
#pragma unroll
    for (int i = 0; i < 4; ++i)
      gload_lds16(Bg + (size_t)(i * 64 + srow) * ldb + t * 32 + g * 8,
                  Bb + i * 4096 + tid * 16);
  };

  auto CMP = [&](int p) {
    const char* Ab = lds + p * 24576;
    const char* Bb = lds + p * 24576 + 8192 + w * 4096;
    bf16x8 a[8], bq[4];
#pragma unroll
    for (int am = 0; am < 8; ++am) a[am] = *(const bf16x8*)(Ab + am * 1024 + aoff);
#pragma unroll
    for (int fn = 0; fn < 4; ++fn) bq[fn] = *(const bf16x8*)(Bb + fn * 1024 + aoff);
    __builtin_amdgcn_s_setprio(1);
#pragma unroll
    for (int am = 0; am < 8; ++am)
#pragma unroll
      for (int fn = 0; fn < 4; ++fn)
        acc[am][fn] = __builtin_amdgcn_mfma_f32_16x16x32_bf16(
            a[am], bq[fn], acc[am][fn], 0, 0, 0);
    __builtin_amdgcn_s_setprio(0);
  };

  STG(0, 0);
  STG(1, 1);
  int pw = 2, pr = 0;
  for (int t = 0; t < nt - 2; ++t) {
    STG(t + 2, pw);
    VMW12;                 // 18 in flight -> retire tile t's 6
    BARX;
    CMP(pr);
    BARX;
    pw = (pw == 2) ? 0 : pw + 1;
    pr = (pr == 2) ? 0 : pr + 1;
  }
  VMW6; BARX; CMP(pr); BARX;   // 12 in flight -> retire tile nt-2's 6
  pr = (pr == 2) ? 0 : pr + 1;
  VMW0; BARX; CMP(pr);
}

// ------- r5h_3: 128x128 tile, BK=32, TRIPLE-buffer (16KB x3), depth-2 -------
// 4 loads/tile -> 12 in flight; vmcnt(8) retires tile t.
// acc[fm][fn]: row = m0 + wr*64 + fm*16 + (lane>>4)*4 + r;
//              col = n0 + wc*64 + fn*16 + (lane&15)
__device__ __forceinline__ void r5h_loop3(
    const bf16* __restrict__ Ag, int lda,
    const bf16* __restrict__ Bg, int ldb,
    int nt, char* lds, f32x4 (&acc)[4][4])
{
  const int tid = threadIdx.x, lane = tid & 63, wid = tid >> 6;
  const int wr = wid >> 1, wc = wid & 1;
  const int g    = (tid & 3) ^ ((tid >> 3) & 3);
  const int srow = tid >> 2;
  const int l15  = lane & 15, lg = lane >> 4;
  const int aoff = l15 * 64 + ((lg ^ ((l15 >> 1) & 3)) << 4);

  auto STG = [&](int t, int p) {
    char* Ab = lds + p * 16384;
    char* Bb = lds + p * 16384 + 8192;
#pragma unroll
    for (int i = 0; i < 2; ++i) {
      gload_lds16(Ag + (size_t)(i * 64 + srow) * lda + t * 32 + g * 8,
                  Ab + i * 4096 + tid * 16);
      gload_lds16(Bg + (size_t)(i * 64 + srow) * ldb + t * 32 + g * 8,
                  Bb + i * 4096 + tid * 16);
    }
  };

  auto CMP = [&](int p) {
    const char* Ab = lds + p * 16384 + wr * 4096;
    const char* Bb = lds + p * 16384 + 8192 + wc * 4096;
    bf16x8 a[4], bq[4];
#pragma unroll
    for (int fm = 0; fm < 4; ++fm) a[fm] = *(const bf16x8*)(Ab + fm * 1024 + aoff);
#pragma unroll
    for (int fn = 0; fn < 4; ++fn) bq[fn] = *(const bf16x8*)(Bb + fn * 1024 + aoff);
    __builtin_amdgcn_s_setprio(1);
#pragma unroll
    for (int fm = 0; fm < 4; ++fm)
#pragma unroll
      for (int fn = 0; fn < 4; ++fn)
        acc[fm][fn] = __builtin_amdgcn_mfma_f32_16x16x32_bf16(
            a[fm], bq[fn], acc[fm][fn], 0, 0, 0);
    __builtin_amdgcn_s_setprio(0);
  };

  STG(0, 0);
  STG(1, 1);
  int pw = 2, pr = 0;
  for (int t = 0; t < nt - 2; ++t) {
    STG(t + 2, pw);
    VMW8;                  // 12 in flight -> retire tile t's 4
    BARX;
    CMP(pr);
    BARX;
    pw = (pw == 2) ? 0 : pw + 1;
    pr = (pr == 2) ? 0 : pr + 1;
  }
  VMW4; BARX; CMP(pr); BARX;   // 8 in flight -> retire tile nt-2's 4
  pr = (pr == 2) ? 0 : pr + 1;
  VMW0; BARX; CMP(pr);
}

// ------- r5q_3: 128x64 tile, BK=32, TRIPLE-buffer (12KB x3), depth-2 --------
// Thin-N tail-balancer (verified r14). A-staging identical to r5h; B = one
// 4KB load/tile. 3 loads/tile -> 9 in flight; vmcnt(6) retires tile t.
// acc[fm][fn]: row = m0 + wr*64 + fm*16 + r4 + rr; col = n0 + wc*32 + fn*16 + cn
__device__ __forceinline__ void r5q_loop3(
    const bf16* __restrict__ Ag, int lda,
    const bf16* __restrict__ Bg, int ldb,
    int nt, char* lds, f32x4 (&acc)[4][2])
{
  const int tid = threadIdx.x, lane = tid & 63, wid = tid >> 6;
  const int wr = wid >> 1, wc = wid & 1;
  const int g    = (tid & 3) ^ ((tid >> 3) & 3);
  const int srow = tid >> 2;
  const int l15  = lane & 15, lg = lane >> 4;
  const int aoff = l15 * 64 + ((lg ^ ((l15 >> 1) & 3)) << 4);

  auto STG = [&](int t, int p) {
    char* Ab = lds + p * 12288;
    char* Bb = lds + p * 12288 + 8192;
#pragma unroll
    for (int i = 0; i < 2; ++i)
      gload_lds16(Ag + (size_t)(i * 64 + srow) * lda + t * 32 + g * 8,
                  Ab + i * 4096 + tid * 16);
    gload_lds16(Bg + (size_t)srow * ldb + t * 32 + g * 8, Bb + tid * 16);
  };

  auto CMP = [&](int p) {
    const char* Ab = lds + p * 12288 + wr * 4096;
    const char* Bb = lds + p * 12288 + 8192 + wc * 2048;
    bf16x8 a[4], bq[2];
#pragma unroll
    for (int fm = 0; fm < 4; ++fm) a[fm] = *(const bf16x8*)(Ab + fm * 1024 + aoff);
#pragma unroll
    for (int fn = 0; fn < 2; ++fn) bq[fn] = *(const bf16x8*)(Bb + fn * 1024 + aoff);
    __builtin_amdgcn_s_setprio(1);
#pragma unroll
    for (int fm = 0; fm < 4; ++fm)
#pragma unroll
      for (int fn = 0; fn < 2; ++fn)
        acc[fm][fn] = __builtin_amdgcn_mfma_f32_16x16x32_bf16(
            a[fm], bq[fn], acc[fm][fn], 0, 0, 0);
    __builtin_amdgcn_s_setprio(0);
  };

  STG(0, 0);
  STG(1, 1);
  int pw = 2, pr = 0;
  for (int t = 0; t < nt - 2; ++t) {
    STG(t + 2, pw);
    VMW6;                  // 9 in flight -> retire tile t's 3
    BARX;
    CMP(pr);
    BARX;
    pw = (pw == 2) ? 0 : pw + 1;
    pr = (pr == 2) ? 0 : pr + 1;
  }
  VMW3; BARX; CMP(pr); BARX;   // 6 in flight -> retire tile nt-2's 3
  pr = (pr == 2) ? 0 : pr + 1;
  VMW0; BARX; CMP(pr);
}

__device__ __forceinline__ void acc_zero4(f32x4 (&acc)[4][4]) {
#pragma unroll
  for (int i = 0; i < 4; ++i)
#pragma unroll
    for (int j = 0; j < 4; ++j)
      acc[i][j] = (f32x4){0.f, 0.f, 0.f, 0.f};
}

// ---- prep: MT split-2 partials | x cast | Wv transpose | RS zero -----------
// blocks [0,128):    MT partial: tile=bid>>1 (8x8 of 128^2), K-slice s=bid&1
//                    (K=512, 16 K-steps, reg-prefetched ~1700cy/step -> ~11us
//                    tail, hidden under ~17us cast). Split-2 (was split-4 in
//                    r10-r17): halves mtred's plane traffic (16->8MB).
// blocks [128,4224): x cast f32->bf16, 8 elems/thread.
// blocks [4224,5248): Wv 32x32 transpose-cast tiles -> WTv.
// block  5248:       zero RS (32KB).
__global__ __launch_bounds__(256) void k_prep(const float* __restrict__ x,
                                              bf16* __restrict__ xb,
                                              const float* __restrict__ Wq,
                                              const float* __restrict__ Wk,
                                              const float* __restrict__ Wv,
                                              bf16* __restrict__ WTv,
                                              float* __restrict__ MTp,
                                              float* __restrict__ RS) {
  __shared__ __align__(16) char lds[16384];
  const int bid = blockIdx.x;
  const int tid = threadIdx.x;

  if (bid < 128) {
    // ---- MT partial: MTp[s][j'][j] = sum_{d in slice s} Wk[j'][d]*Wq[j][d] --
    const int tile = bid >> 1, s = bid & 1;
    const int m0 = (tile >> 3) * 128, n0 = (tile & 7) * 128;
    const int k0 = s * 512;
    const int lane = tid & 63, wid = tid >> 6;
    const int wr = wid >> 1, wc = wid & 1;
    const int g    = (tid & 3) ^ ((tid >> 3) & 3);
    const int srow = tid >> 2;
    const int l15  = lane & 15, lg = lane >> 4;
    const int aoff = l15 * 64 + ((lg ^ ((l15 >> 1) & 3)) << 4);

    const float* ap0 = Wk + (size_t)(m0 + srow) * DI + k0 + g * 8;
    const float* ap1 = Wk + (size_t)(m0 + 64 + srow) * DI + k0 + g * 8;
    const float* bp0 = Wq + (size_t)(n0 + srow) * DI + k0 + g * 8;
    const float* bp1 = Wq + (size_t)(n0 + 64 + srow) * DI + k0 + g * 8;

    f32x4 acc[4][4];
    acc_zero4(acc);

    // preload step 0
    float4 A00 = *(const float4*)(ap0), A01 = *(const float4*)(ap0 + 4);
    float4 A10 = *(const float4*)(ap1), A11 = *(const float4*)(ap1 + 4);
    float4 B00 = *(const float4*)(bp0), B01 = *(const float4*)(bp0 + 4);
    float4 B10 = *(const float4*)(bp1), B11 = *(const float4*)(bp1 + 4);

    for (int t = 0; t < 16; ++t) {
      float4 nA00, nA01, nA10, nA11, nB00, nB01, nB10, nB11;
      if (t < 15) {              // issue next-step loads early (hide under MFMA)
        const int o = (t + 1) * 32;
        nA00 = *(const float4*)(ap0 + o); nA01 = *(const float4*)(ap0 + o + 4);
        nA10 = *(const float4*)(ap1 + o); nA11 = *(const float4*)(ap1 + o + 4);
        nB00 = *(const float4*)(bp0 + o); nB01 = *(const float4*)(bp0 + o + 4);
        nB10 = *(const float4*)(bp1 + o); nB11 = *(const float4*)(bp1 + o + 4);
      }
      // stage current step (reg -> cvt -> LDS), r5h layout
      *(bf16x8*)(lds + tid * 16)         = cvt8(A00, A01);
      *(bf16x8*)(lds + 4096 + tid * 16)  = cvt8(A10, A11);
      *(bf16x8*)(lds + 8192 + tid * 16)  = cvt8(B00, B01);
      *(bf16x8*)(lds + 12288 + tid * 16) = cvt8(B10, B11);
      __syncthreads();
      {
        const char* Ab = lds + wr * 4096;
        const char* Bb = lds + 8192 + wc * 4096;
        bf16x8 a[4], bq[4];
#pragma unroll
        for (int fm = 0; fm < 4; ++fm) a[fm] = *(const bf16x8*)(Ab + fm * 1024 + aoff);
#pragma unroll
        for (int fn = 0; fn < 4; ++fn) bq[fn] = *(const bf16x8*)(Bb + fn * 1024 + aoff);
#pragma unroll
        for (int fm = 0; fm < 4; ++fm)
#pragma unroll
          for (int fn = 0; fn < 4; ++fn)
            acc[fm][fn] = __builtin_amdgcn_mfma_f32_16x16x32_bf16(
                a[fm], bq[fn], acc[fm][fn], 0, 0, 0);
      }
      __syncthreads();
      A00 = nA00; A01 = nA01; A10 = nA10; A11 = nA11;
      B00 = nB00; B01 = nB01; B10 = nB10; B11 = nB11;
    }

    float* MPs = MTp + (size_t)s * (1024 * 1024);
    const int r4 = (lane >> 4) * 4, cn = lane & 15;
#pragma unroll
    for (int fm = 0; fm < 4; ++fm)
#pragma unroll
      for (int fn = 0; fn < 4; ++fn) {
        const int rowb = m0 + wr * 64 + fm * 16 + r4;
        const int col  = n0 + wc * 64 + fn * 16 + cn;
#pragma unroll
        for (int rr = 0; rr < 4; ++rr)
          MPs[(size_t)(rowb + rr) * 1024 + col] = acc[fm][fn][rr];
      }
  } else if (bid < 4224) {
    // ---- x cast ----
    const size_t i = ((size_t)(bid - 128) * 256 + tid) * 8;
    const float4 a = *(const float4*)(x + i);
    const float4 c = *(const float4*)(x + i + 4);
    *(bf16x8*)(xb + i) = cvt8(a, c);
  } else if (bid < 5248) {
    // ---- Wv transpose-cast: 32x32 tile ----
    float (*t)[33] = (float (*)[33])lds;
    const int tt = bid - 4224;
    const int c0 = (tt & 31) * 32, k0 = (tt >> 5) * 32;
    const int tx = tid & 31, ty = tid >> 5;   // 32 x 8
#pragma unroll
    for (int i = 0; i < 4; ++i)
      t[ty + 8 * i][tx] = Wv[(size_t)(k0 + ty + 8 * i) * DI + c0 + tx];
    __syncthreads();
#pragma unroll
    for (int i = 0; i < 4; ++i)
      WTv[(size_t)(c0 + ty + 8 * i) * DI + k0 + tx] = (bf16)t[tx][ty + 8 * i];
  } else {
    // ---- RS zero: 8192 f32 = 32 f32/thread ----
    float4 z = {0.f, 0.f, 0.f, 0.f};
#pragma unroll
    for (int i = 0; i < 8; ++i)
      *(float4*)(RS + (size_t)tid * 32 + i * 4) = z;
  }
}

// ---- mtred: reduce 2 MTp planes (f32) -> MT (bf16), 512 blocks -------------
__global__ __launch_bounds__(256) void k_mtred(const float* __restrict__ MTp,
                                               bf16* __restrict__ MT) {
  const size_t i = ((size_t)blockIdx.x * 256 + threadIdx.x) * 8;
  const float* p = MTp + (size_t)(1024 * 1024) + i;
  float4 a = *(const float4*)(MTp + i);
  float4 b = *(const float4*)(MTp + i + 4);
  const float4 c = *(const float4*)p;
  const float4 d = *(const float4*)(p + 4);
  a.x += c.x; a.y += c.y; a.z += c.z; a.w += c.w;
  b.x += d.x; b.y += d.y; b.z += d.z; b.w += d.w;
  *(bf16x8*)(MT + i) = cvt8(a, b);
}

// ------- T|V fused: 128x256 r5 tiles, 512 blocks, 2 blk/CU, 1.0 rounds ------
// n0 < 1024: T = X*M (row-major, B-operand = MT);  n0 >= 1024: V (stored V^T).
__global__ __launch_bounds__(256, 2) void k_tv(const bf16* __restrict__ X,
                                               const bf16* __restrict__ MT,
                                               const bf16* __restrict__ WTv,
                                               bf16* __restrict__ T,
                                               bf16* __restrict__ VT) {
  __shared__ __align__(16) char lds[73728];   // 3 x (A 8KB | B 16KB)
  const int bid  = blockIdx.x;
  // XCD-aware bijective swizzle: 512 = 8 * 64
  const int wgid = (bid & 7) * 64 + (bid >> 3);
  const int m0 = (wgid >> 3) * 128;
  const int n0 = (wgid & 7) * 256;

  const bf16* Bg = (n0 < 1024) ? MT + (size_t)n0 * 1024
                               : WTv + (size_t)(n0 - 1024) * 1024;

  f32x4 acc[8][4];
#pragma unroll
  for (int i = 0; i < 8; ++i)
#pragma unroll
    for (int j = 0; j < 4; ++j)
      acc[i][j] = (f32x4){0.f, 0.f, 0.f, 0.f};

  r5_loop3(X + (size_t)m0 * 1024, 1024, Bg, 1024, 32, lds, acc);

  const int lane = threadIdx.x & 63, w = threadIdx.x >> 6;
  const int r4 = (lane >> 4) * 4;
  const int cn = lane & 15;
  if (n0 < 1024) {
#pragma unroll
    for (int am = 0; am < 8; ++am) {
      const int row = m0 + am * 16 + r4;
#pragma unroll
      for (int fn = 0; fn < 4; ++fn) {
        const int n = n0 + w * 64 + fn * 16 + cn;
        const size_t base = (size_t)row * 1024 + n;
#pragma unroll
        for (int r = 0; r < 4; ++r)
          T[base + (size_t)r * 1024] = (bf16)acc[am][fn][r];
      }
    }
  } else {
    const int b_ = m0 >> 11;
    const int sb = m0 & 2047;
#pragma unroll
    for (int am = 0; am < 8; ++am)
#pragma unroll
      for (int fn = 0; fn < 4; ++fn) {
        const int d  = (n0 - 1024) + w * 64 + fn * 16 + cn;
        const int s0 = sb + am * 16 + r4;
        ushort4 pk;
        pk.x = __builtin_bit_cast(unsigned short, (bf16)acc[am][fn][0]);
        pk.y = __builtin_bit_cast(unsigned short, (bf16)acc[am][fn][1]);
        pk.z = __builtin_bit_cast(unsigned short, (bf16)acc[am][fn][2]);
        pk.w = __builtin_bit_cast(unsigned short, (bf16)acc[am][fn][3]);
        *(ushort4*)(VT + ((size_t)b_ * DOUT + d) * SS + s0) = pk;
      }
  }
}

// ---- scores = T.X^T, fused exp: causal mask + exp(s*scale) + row-sum -------
// Hybrid tail-balanced work-list (576 blocks = per-XCD {64 full r5h + 8 thin
// r5q halves of 4 tiles}).
__global__ __launch_bounds__(256, 3) void k_gemm_qk(const bf16* __restrict__ T,
                                                    const bf16* __restrict__ XB,
                                                    bf16* __restrict__ E,
                                                    float* __restrict__ RS) {
  __shared__ __align__(16) char lds[49152];
  const int c  = blockIdx.x & 7;          // XCD
  const int li = blockIdx.x >> 3;         // 0..71 within XCD chunk
  const bool full = (li < 64);
  const int gt = full ? (c * 68 + li) : (c * 68 + 64 + ((li - 64) >> 1));
  const int nh = full ? 0 : ((li - 64) & 1);

  const int b = gt / 136;
  int r = gt % 136;
  int i = 0;
  for (;;) { const int cnt = i + 1; if (r < cnt) break; r -= cnt; ++i; }
  const int m0 = i * 128;

  bf16* Eb = E + (size_t)b * SS * SS;
  float* RSb = RS + (size_t)b * SS;
  const float scale = 0.03125f;  // 1/sqrt(1024)
  const int lane = threadIdx.x & 63, wid = threadIdx.x >> 6;
  const int wr = wid >> 1, wc = wid & 1;
  const int r4 = (lane >> 4) * 4, cn = lane & 15;

  float rsum[4][4];
#pragma unroll
  for (int fm = 0; fm < 4; ++fm)
#pragma unroll
    for (int rr = 0; rr < 4; ++rr) rsum[fm][rr] = 0.f;

  if (full) {
    const int n0 = r * 128;
    f32x4 acc[4][4];
    acc_zero4(acc);
    r5h_loop3(T  + ((size_t)b * SS + m0) * 1024, 1024,
              XB + ((size_t)b * SS + n0) * 1024, 1024, 32, lds, acc);
#pragma unroll
    for (int fm = 0; fm < 4; ++fm)
#pragma unroll
      for (int fn = 0; fn < 4; ++fn) {
        const int n = n0 + wc * 64 + fn * 16 + cn;
        const int rowb = m0 + wr * 64 + fm * 16 + r4;
        const size_t bofs = (size_t)rowb * SS + n;
#pragma unroll
        for (int rr = 0; rr < 4; ++rr) {
          const float e = (n <= rowb + rr) ? __expf(acc[fm][fn][rr] * scale) : 0.f;
          Eb[bofs + (size_t)rr * SS] = (bf16)e;
          rsum[fm][rr] += e;
        }
      }
  } else {
    const int n0 = r * 128 + nh * 64;
    f32x4 acc[4][2];
#pragma unroll
    for (int ii = 0; ii < 4; ++ii)
#pragma unroll
      for (int jj = 0; jj < 2; ++jj)
        acc[ii][jj] = (f32x4){0.f, 0.f, 0.f, 0.f};
    r5q_loop3(T  + ((size_t)b * SS + m0) * 1024, 1024,
              XB + ((size_t)b * SS + n0) * 1024, 1024, 32, lds, acc);
#pragma unroll
    for (int fm = 0; fm < 4; ++fm)
#pragma unroll
      for (int fn = 0; fn < 2; ++fn) {
        const int n = n0 + wc * 32 + fn * 16 + cn;
        const int rowb = m0 + wr * 64 + fm * 16 + r4;
        const size_t bofs = (size_t)rowb * SS + n;
#pragma unroll
        for (int rr = 0; rr < 4; ++rr) {
          const float e = (n <= rowb + rr) ? __expf(acc[fm][fn][rr] * scale) : 0.f;
          Eb[bofs + (size_t)rr * SS] = (bf16)e;
          rsum[fm][rr] += e;
        }
      }
  }

  // reduce over the 16 cn-lanes (same row group: lane>>4 invariant under xor<16)
#pragma unroll
  for (int fm = 0; fm < 4; ++fm)
#pragma unroll
    for (int rr = 0; rr < 4; ++rr) {
      float s = rsum[fm][rr];
      s += __shfl_xor(s, 1);
      s += __shfl_xor(s, 2);
      s += __shfl_xor(s, 4);
      s += __shfl_xor(s, 8);
      if (cn == 0)
        atomicAdd(&RSb[m0 + wr * 64 + fm * 16 + r4 + rr], s);
    }
}

// ---------------- PV: r5h3, anti-correlated balance (512 blocks) ------------
// Consumes unnormalized E; divides by RS[row] in epilogue.
// Same-j blocks land on one XCD by construction (bid mod 8 = j) -> VT panel
// reuse is XCD-local; (i, 15-i) pairing balances per-CU work at 68 K-steps.
__global__ __launch_bounds__(256, 3) void k_gemm_pv(const bf16* __restrict__ P,
                                                    const bf16* __restrict__ VT,
                                                    const float* __restrict__ RS,
                                                    float* __restrict__ Out) {
  __shared__ __align__(16) char lds[49152];
  const int wfl = blockIdx.x;
  const int h = wfl >> 8;
  const int r = wfl & 255;
  const int b = r >> 6;
  const int t = r & 63;
  const int ip = t >> 3;
  const int j = t & 7;
  const int i = h ? (15 - ip) : ip;
  const int m0 = i * 128, n0 = j * 128;
  const int nt = 4 * (i + 1);     // s-tiles [0, (i+1)*128)

  f32x4 acc[4][4];
  acc_zero4(acc);
  r5h_loop3(P  + (size_t)b * SS * SS   + (size_t)m0 * SS, SS,
            VT + (size_t)b * DOUT * SS + (size_t)n0 * SS, SS,
            nt, lds, acc);

  float* Ob = Out + (size_t)b * SS * DOUT;
  const float* RSb = RS + (size_t)b * SS;
  const int lane = threadIdx.x & 63, wid = threadIdx.x >> 6;
  const int wr = wid >> 1, wc = wid & 1;
  const int r4 = (lane >> 4) * 4, cn = lane & 15;
#pragma unroll
  for (int fm = 0; fm < 4; ++fm) {
    const int rowb = m0 + wr * 64 + fm * 16 + r4;
    const float4 rs4 = *(const float4*)(RSb + rowb);
    float inv[4];
    inv[0] = 1.0f / rs4.x; inv[1] = 1.0f / rs4.y;
    inv[2] = 1.0f / rs4.z; inv[3] = 1.0f / rs4.w;
#pragma unroll
    for (int fn = 0; fn < 4; ++fn) {
      const int n = n0 + wc * 64 + fn * 16 + cn;
      const size_t bofs = (size_t)rowb * DOUT + n;
#pragma unroll
      for (int rr = 0; rr < 4; ++rr)
        Ob[bofs + (size_t)rr * DOUT] = acc[fm][fn][rr] * inv[rr];
    }
  }
}

// ---------------- launch ----------------
extern "C" void kernel_launch(void* const* d_in, const int* in_sizes, int n_in,
                              void* d_out, int out_size, void* d_ws, size_t ws_size,
                              hipStream_t stream) {
  const float* x  = (const float*)d_in[0];
  const float* Wq = (const float*)d_in[1];
  const float* Wk = (const float*)d_in[2];
  const float* Wv = (const float*)d_in[3];
  float* out = (float*)d_out;
  char* ws = (char*)d_ws;

  bf16*  T   = (bf16*)(ws);                        // 16 MB [8192][1024]  X*M
  bf16*  VT  = (bf16*)(ws + ((size_t)16 << 20));   // 16 MB [4][1024][2048]
  bf16*  E   = (bf16*)(ws + ((size_t)32 << 20));   // 32 MB unnorm exp scores
  float* MTp = (float*)(ws + ((size_t)32 << 20));  //  8 MB (aliases E; dead before qk)
  bf16*  XB  = (bf16*)(ws + ((size_t)64 << 20));   // 16 MB (live through qk!)
  bf16*  WTv = (bf16*)(ws + ((size_t)80 << 20));   //  2 MB transposed bf16 Wv
  bf16*  MT  = (bf16*)(ws + ((size_t)82 << 20));   //  2 MB M^T = Wk.Wq^T (bf16)
  float* RS  = (float*)(ws + ((size_t)84 << 20));  // 32 KB row sums [4][2048]

  k_prep<<<5249, 256, 0, stream>>>(x, XB, Wq, Wk, Wv, WTv, MTp, RS);
  k_mtred<<<512, 256, 0, stream>>>(MTp, MT);
  k_tv<<<512, 256, 0, stream>>>(XB, MT, WTv, T, VT);
  k_gemm_qk<<<576, 256, 0, stream>>>(T, XB, E, RS);
  k_gemm_pv<<<512, 256, 0, stream>>>(E, VT, RS, out);
}

// Round 19
// 124.778 us; speedup vs baseline: 1.0078x; 1.0078x over previous
//
#include <hip/hip_runtime.h>
#include <hip/hip_bf16.h>
#include <stdint.h>

typedef __bf16 bf16;
typedef bf16 bf16x8 __attribute__((ext_vector_type(8)));
typedef float f32x4 __attribute__((ext_vector_type(4)));

#define NB   4
#define SS   2048
#define DI   1024
#define DOUT 1024

__device__ __forceinline__ void gload_lds16(const void* g, void* l) {
  __builtin_amdgcn_global_load_lds(
      (const __attribute__((address_space(1))) void*)g,
      (__attribute__((address_space(3))) void*)l, 16, 0, 0);
}

#define BARX  { __builtin_amdgcn_s_barrier(); __builtin_amdgcn_sched_barrier(0); }
#define VMW12 asm volatile("s_waitcnt vmcnt(12)" ::: "memory")
#define VMW8  asm volatile("s_waitcnt vmcnt(8)"  ::: "memory")
#define VMW6  asm volatile("s_waitcnt vmcnt(6)"  ::: "memory")
#define VMW4  asm volatile("s_waitcnt vmcnt(4)"  ::: "memory")
#define VMW3  asm volatile("s_waitcnt vmcnt(3)"  ::: "memory")
#define VMW0  asm volatile("s_waitcnt vmcnt(0)"  ::: "memory")

__device__ __forceinline__ bf16x8 cvt8(float4 a, float4 b) {
  bf16x8 v;
  v[0] = (bf16)a.x; v[1] = (bf16)a.y; v[2] = (bf16)a.z; v[3] = (bf16)a.w;
  v[4] = (bf16)b.x; v[5] = (bf16)b.y; v[6] = (bf16)b.z; v[7] = (bf16)b.w;
  return v;
}

// ------- r5_3: 128x256 tile, BK=32, TRIPLE-buffer (24KB x3), depth-2 --------
// 6 loads/tile -> 18 in flight; vmcnt(12) retires tile t.
// acc[am][fn]: row = m0 + am*16 + (lane>>4)*4 + r; col = n0 + w*64 + fn*16 + (lane&15)
// Conflict-free 64B-row LDS layout (r16 lesson: 128B-row linear = 16-way
// bank conflict, 9.4M/dispatch; this layout measures 0).
__device__ __forceinline__ void r5_loop3(
    const bf16* __restrict__ Ag, int lda,
    const bf16* __restrict__ Bg, int ldb,
    int nt, char* lds, f32x4 (&acc)[8][4])
{
  const int tid = threadIdx.x, lane = tid & 63, w = tid >> 6;
  const int g    = (tid & 3) ^ ((tid >> 3) & 3);
  const int srow = tid >> 2;
  const int l15  = lane & 15, lg = lane >> 4;
  const int aoff = l15 * 64 + ((lg ^ ((l15 >> 1) & 3)) << 4);

  auto STG = [&](int t, int p) {
    char* Ab = lds + p * 24576;
    char* Bb = lds + p * 24576 + 8192;
#pragma unroll
    for (int i = 0; i < 2; ++i)
      gload_lds16(Ag + (size_t)(i * 64 + srow) * lda + t * 32 + g * 8,
                  Ab + i * 4096 + tid * 16);
#pragma unroll
    for (int i = 0; i < 4; ++i)
      gload_lds16(Bg + (size_t)(i * 64 + srow) * ldb + t * 32 + g * 8,
                  Bb + i * 4096 + tid * 16);
  };

  auto CMP = [&](int p) {
    const char* Ab = lds + p * 24576;
    const char* Bb = lds + p * 24576 + 8192 + w * 4096;
    bf16x8 a[8], bq[4];
#pragma unroll
    for (int am = 0; am < 8; ++am) a[am] = *(const bf16x8*)(Ab + am * 1024 + aoff);
#pragma unroll
    for (int fn = 0; fn < 4; ++fn) bq[fn] = *(const bf16x8*)(Bb + fn * 1024 + aoff);
    __builtin_amdgcn_s_setprio(1);
#pragma unroll
    for (int am = 0; am < 8; ++am)
#pragma unroll
      for (int fn = 0; fn < 4; ++fn)
        acc[am][fn] = __builtin_amdgcn_mfma_f32_16x16x32_bf16(
            a[am], bq[fn], acc[am][fn], 0, 0, 0);
    __builtin_amdgcn_s_setprio(0);
  };

  STG(0, 0);
  STG(1, 1);
  int pw = 2, pr = 0;
  for (int t = 0; t < nt - 2; ++t) {
    STG(t + 2, pw);
    VMW12;                 // 18 in flight -> retire tile t's 6
    BARX;
    CMP(pr);
    BARX;
    pw = (pw == 2) ? 0 : pw + 1;
    pr = (pr == 2) ? 0 : pr + 1;
  }
  VMW6; BARX; CMP(pr); BARX;   // 12 in flight -> retire tile nt-2's 6
  pr = (pr == 2) ? 0 : pr + 1;
  VMW0; BARX; CMP(pr);
}

// ------- r5h_3: 128x128 tile, BK=32, TRIPLE-buffer (16KB x3), depth-2 -------
// 4 loads/tile -> 12 in flight; vmcnt(8) retires tile t.
// acc[fm][fn]: row = m0 + wr*64 + fm*16 + (lane>>4)*4 + r;
//              col = n0 + wc*64 + fn*16 + (lane&15)
__device__ __forceinline__ void r5h_loop3(
    const bf16* __restrict__ Ag, int lda,
    const bf16* __restrict__ Bg, int ldb,
    int nt, char* lds, f32x4 (&acc)[4][4])
{
  const int tid = threadIdx.x, lane = tid & 63, wid = tid >> 6;
  const int wr = wid >> 1, wc = wid & 1;
  const int g    = (tid & 3) ^ ((tid >> 3) & 3);
  const int srow = tid >> 2;
  const int l15  = lane & 15, lg = lane >> 4;
  const int aoff = l15 * 64 + ((lg ^ ((l15 >> 1) & 3)) << 4);

  auto STG = [&](int t, int p) {
    char* Ab = lds + p * 16384;
    char* Bb = lds + p * 16384 + 8192;
#pragma unroll
    for (int i = 0; i < 2; ++i) {
      gload_lds16(Ag + (size_t)(i * 64 + srow) * lda + t * 32 + g * 8,
                  Ab + i * 4096 + tid * 16);
      gload_lds16(Bg + (size_t)(i * 64 + srow) * ldb + t * 32 + g * 8,
                  Bb + i * 4096 + tid * 16);
    }
  };

  auto CMP = [&](int p) {
    const char* Ab = lds + p * 16384 + wr * 4096;
    const char* Bb = lds + p * 16384 + 8192 + wc * 4096;
    bf16x8 a[4], bq[4];
#pragma unroll
    for (int fm = 0; fm < 4; ++fm) a[fm] = *(const bf16x8*)(Ab + fm * 1024 + aoff);
#pragma unroll
    for (int fn = 0; fn < 4; ++fn) bq[fn] = *(const bf16x8*)(Bb + fn * 1024 + aoff);
    __builtin_amdgcn_s_setprio(1);
#pragma unroll
    for (int fm = 0; fm < 4; ++fm)
#pragma unroll
      for (int fn = 0; fn < 4; ++fn)
        acc[fm][fn] = __builtin_amdgcn_mfma_f32_16x16x32_bf16(
            a[fm], bq[fn], acc[fm][fn], 0, 0, 0);
    __builtin_amdgcn_s_setprio(0);
  };

  STG(0, 0);
  STG(1, 1);
  int pw = 2, pr = 0;
  for (int t = 0; t < nt - 2; ++t) {
    STG(t + 2, pw);
    VMW8;                  // 12 in flight -> retire tile t's 4
    BARX;
    CMP(pr);
    BARX;
    pw = (pw == 2) ? 0 : pw + 1;
    pr = (pr == 2) ? 0 : pr + 1;
  }
  VMW4; BARX; CMP(pr); BARX;   // 8 in flight -> retire tile nt-2's 4
  pr = (pr == 2) ? 0 : pr + 1;
  VMW0; BARX; CMP(pr);
}

// ------- r5q_3: 128x64 tile, BK=32, TRIPLE-buffer (12KB x3), depth-2 --------
// Thin-N tail-balancer (verified r14). A-staging identical to r5h; B = one
// 4KB load/tile. 3 loads/tile -> 9 in flight; vmcnt(6) retires tile t.
// acc[fm][fn]: row = m0 + wr*64 + fm*16 + r4 + rr; col = n0 + wc*32 + fn*16 + cn
__device__ __forceinline__ void r5q_loop3(
    const bf16* __restrict__ Ag, int lda,
    const bf16* __restrict__ Bg, int ldb,
    int nt, char* lds, f32x4 (&acc)[4][2])
{
  const int tid = threadIdx.x, lane = tid & 63, wid = tid >> 6;
  const int wr = wid >> 1, wc = wid & 1;
  const int g    = (tid & 3) ^ ((tid >> 3) & 3);
  const int srow = tid >> 2;
  const int l15  = lane & 15, lg = lane >> 4;
  const int aoff = l15 * 64 + ((lg ^ ((l15 >> 1) & 3)) << 4);

  auto STG = [&](int t, int p) {
    char* Ab = lds + p * 12288;
    char* Bb = lds + p * 12288 + 8192;
#pragma unroll
    for (int i = 0; i < 2; ++i)
      gload_lds16(Ag + (size_t)(i * 64 + srow) * lda + t * 32 + g * 8,
                  Ab + i * 4096 + tid * 16);
    gload_lds16(Bg + (size_t)srow * ldb + t * 32 + g * 8, Bb + tid * 16);
  };

  auto CMP = [&](int p) {
    const char* Ab = lds + p * 12288 + wr * 4096;
    const char* Bb = lds + p * 12288 + 8192 + wc * 2048;
    bf16x8 a[4], bq[2];
#pragma unroll
    for (int fm = 0; fm < 4; ++fm) a[fm] = *(const bf16x8*)(Ab + fm * 1024 + aoff);
#pragma unroll
    for (int fn = 0; fn < 2; ++fn) bq[fn] = *(const bf16x8*)(Bb + fn * 1024 + aoff);
    __builtin_amdgcn_s_setprio(1);
#pragma unroll
    for (int fm = 0; fm < 4; ++fm)
#pragma unroll
      for (int fn = 0; fn < 2; ++fn)
        acc[fm][fn] = __builtin_amdgcn_mfma_f32_16x16x32_bf16(
            a[fm], bq[fn], acc[fm][fn], 0, 0, 0);
    __builtin_amdgcn_s_setprio(0);
  };

  STG(0, 0);
  STG(1, 1);
  int pw = 2, pr = 0;
  for (int t = 0; t < nt - 2; ++t) {
    STG(t + 2, pw);
    VMW6;                  // 9 in flight -> retire tile t's 3
    BARX;
    CMP(pr);
    BARX;
    pw = (pw == 2) ? 0 : pw + 1;
    pr = (pr == 2) ? 0 : pr + 1;
  }
  VMW3; BARX; CMP(pr); BARX;   // 6 in flight -> retire tile nt-2's 3
  pr = (pr == 2) ? 0 : pr + 1;
  VMW0; BARX; CMP(pr);
}

__device__ __forceinline__ void acc_zero4(f32x4 (&acc)[4][4]) {
#pragma unroll
  for (int i = 0; i < 4; ++i)
#pragma unroll
    for (int j = 0; j < 4; ++j)
      acc[i][j] = (f32x4){0.f, 0.f, 0.f, 0.f};
}

// ---- prep: MT split-4 partials | x cast | Wv transpose | RS zero -----------
// blocks [0,256):    MT partial: tile=bid>>2 (8x8 of 128^2), K-slice s=bid&3
//                    (K=256, 8 K-steps, reg-prefetched staging ~1700cy/step
//                    -> ~6us tail hidden under ~17us cast). Plain plane
//                    stores. No atomics (r6 lesson), no fences (r8 lesson).
// blocks [256,4352): x cast f32->bf16, 8 elems/thread.
// blocks [4352,5376): Wv 32x32 transpose-cast tiles -> WTv.
// block  5376:       zero RS (32KB) -- replaces the hipMemsetAsync dispatch.
__global__ __launch_bounds__(256) void k_prep(const float* __restrict__ x,
                                              bf16* __restrict__ xb,
                                              const float* __restrict__ Wq,
                                              const float* __restrict__ Wk,
                                              const float* __restrict__ Wv,
                                              bf16* __restrict__ WTv,
                                              float* __restrict__ MTp,
                                              float* __restrict__ RS) {
  __shared__ __align__(16) char lds[16384];
  const int bid = blockIdx.x;
  const int tid = threadIdx.x;

  if (bid < 256) {
    // ---- MT partial: MTp[s][j'][j] = sum_{d in slice s} Wk[j'][d]*Wq[j][d] --
    const int tile = bid >> 2, s = bid & 3;
    const int m0 = (tile >> 3) * 128, n0 = (tile & 7) * 128;
    const int k0 = s * 256;
    const int lane = tid & 63, wid = tid >> 6;
    const int wr = wid >> 1, wc = wid & 1;
    const int g    = (tid & 3) ^ ((tid >> 3) & 3);
    const int srow = tid >> 2;
    const int l15  = lane & 15, lg = lane >> 4;
    const int aoff = l15 * 64 + ((lg ^ ((l15 >> 1) & 3)) << 4);

    const float* ap0 = Wk + (size_t)(m0 + srow) * DI + k0 + g * 8;
    const float* ap1 = Wk + (size_t)(m0 + 64 + srow) * DI + k0 + g * 8;
    const float* bp0 = Wq + (size_t)(n0 + srow) * DI + k0 + g * 8;
    const float* bp1 = Wq + (size_t)(n0 + 64 + srow) * DI + k0 + g * 8;

    f32x4 acc[4][4];
    acc_zero4(acc);

    // preload step 0
    float4 A00 = *(const float4*)(ap0), A01 = *(const float4*)(ap0 + 4);
    float4 A10 = *(const float4*)(ap1), A11 = *(const float4*)(ap1 + 4);
    float4 B00 = *(const float4*)(bp0), B01 = *(const float4*)(bp0 + 4);
    float4 B10 = *(const float4*)(bp1), B11 = *(const float4*)(bp1 + 4);

    for (int t = 0; t < 8; ++t) {
      float4 nA00, nA01, nA10, nA11, nB00, nB01, nB10, nB11;
      if (t < 7) {               // issue next-step loads early (hide under MFMA)
        const int o = (t + 1) * 32;
        nA00 = *(const float4*)(ap0 + o); nA01 = *(const float4*)(ap0 + o + 4);
        nA10 = *(const float4*)(ap1 + o); nA11 = *(const float4*)(ap1 + o + 4);
        nB00 = *(const float4*)(bp0 + o); nB01 = *(const float4*)(bp0 + o + 4);
        nB10 = *(const float4*)(bp1 + o); nB11 = *(const float4*)(bp1 + o + 4);
      }
      // stage current step (reg -> cvt -> LDS), r5h layout
      *(bf16x8*)(lds + tid * 16)         = cvt8(A00, A01);
      *(bf16x8*)(lds + 4096 + tid * 16)  = cvt8(A10, A11);
      *(bf16x8*)(lds + 8192 + tid * 16)  = cvt8(B00, B01);
      *(bf16x8*)(lds + 12288 + tid * 16) = cvt8(B10, B11);
      __syncthreads();
      {
        const char* Ab = lds + wr * 4096;
        const char* Bb = lds + 8192 + wc * 4096;
        bf16x8 a[4], bq[4];
#pragma unroll
        for (int fm = 0; fm < 4; ++fm) a[fm] = *(const bf16x8*)(Ab + fm * 1024 + aoff);
#pragma unroll
        for (int fn = 0; fn < 4; ++fn) bq[fn] = *(const bf16x8*)(Bb + fn * 1024 + aoff);
#pragma unroll
        for (int fm = 0; fm < 4; ++fm)
#pragma unroll
          for (int fn = 0; fn < 4; ++fn)
            acc[fm][fn] = __builtin_amdgcn_mfma_f32_16x16x32_bf16(
                a[fm], bq[fn], acc[fm][fn], 0, 0, 0);
      }
      __syncthreads();
      A00 = nA00; A01 = nA01; A10 = nA10; A11 = nA11;
      B00 = nB00; B01 = nB01; B10 = nB10; B11 = nB11;
    }

    float* MPs = MTp + (size_t)s * (1024 * 1024);
    const int r4 = (lane >> 4) * 4, cn = lane & 15;
#pragma unroll
    for (int fm = 0; fm < 4; ++fm)
#pragma unroll
      for (int fn = 0; fn < 4; ++fn) {
        const int rowb = m0 + wr * 64 + fm * 16 + r4;
        const int col  = n0 + wc * 64 + fn * 16 + cn;
#pragma unroll
        for (int rr = 0; rr < 4; ++rr)
          MPs[(size_t)(rowb + rr) * 1024 + col] = acc[fm][fn][rr];
      }
  } else if (bid < 4352) {
    // ---- x cast ----
    const size_t i = ((size_t)(bid - 256) * 256 + tid) * 8;
    const float4 a = *(const float4*)(x + i);
    const float4 c = *(const float4*)(x + i + 4);
    *(bf16x8*)(xb + i) = cvt8(a, c);
  } else if (bid < 5376) {
    // ---- Wv transpose-cast: 32x32 tile ----
    float (*t)[33] = (float (*)[33])lds;
    const int tt = bid - 4352;
    const int c0 = (tt & 31) * 32, k0 = (tt >> 5) * 32;
    const int tx = tid & 31, ty = tid >> 5;   // 32 x 8
#pragma unroll
    for (int i = 0; i < 4; ++i)
      t[ty + 8 * i][tx] = Wv[(size_t)(k0 + ty + 8 * i) * DI + c0 + tx];
    __syncthreads();
#pragma unroll
    for (int i = 0; i < 4; ++i)
      WTv[(size_t)(c0 + ty + 8 * i) * DI + k0 + tx] = (bf16)t[tx][ty + 8 * i];
  } else {
    // ---- RS zero: 8192 f32 = 32 f32/thread ----
    float4 z = {0.f, 0.f, 0.f, 0.f};
#pragma unroll
    for (int i = 0; i < 8; ++i)
      *(float4*)(RS + (size_t)tid * 32 + i * 4) = z;
  }
}

// ---- mtred: reduce 4 MTp planes (f32) -> MT (bf16), 512 blocks -------------
__global__ __launch_bounds__(256) void k_mtred(const float* __restrict__ MTp,
                                               bf16* __restrict__ MT) {
  const size_t i = ((size_t)blockIdx.x * 256 + threadIdx.x) * 8;
  float4 a = *(const float4*)(MTp + i);
  float4 b = *(const float4*)(MTp + i + 4);
#pragma unroll
  for (int s = 1; s < 4; ++s) {
    const float* p = MTp + (size_t)s * (1024 * 1024) + i;
    const float4 c = *(const float4*)p;
    const float4 d = *(const float4*)(p + 4);
    a.x += c.x; a.y += c.y; a.z += c.z; a.w += c.w;
    b.x += d.x; b.y += d.y; b.z += d.z; b.w += d.w;
  }
  *(bf16x8*)(MT + i) = cvt8(a, b);
}

// ------- T|V fused: 128x256 r5 tiles, 512 blocks, 2 blk/CU, 1.0 rounds ------
// n0 < 1024: T = X*M (row-major, B-operand = MT);  n0 >= 1024: V (stored V^T).
__global__ __launch_bounds__(256, 2) void k_tv(const bf16* __restrict__ X,
                                               const bf16* __restrict__ MT,
                                               const bf16* __restrict__ WTv,
                                               bf16* __restrict__ T,
                                               bf16* __restrict__ VT) {
  __shared__ __align__(16) char lds[73728];   // 3 x (A 8KB | B 16KB)
  const int bid  = blockIdx.x;
  // XCD-aware bijective swizzle: 512 = 8 * 64
  const int wgid = (bid & 7) * 64 + (bid >> 3);
  const int m0 = (wgid >> 3) * 128;
  const int n0 = (wgid & 7) * 256;

  const bf16* Bg = (n0 < 1024) ? MT + (size_t)n0 * 1024
                               : WTv + (size_t)(n0 - 1024) * 1024;

  f32x4 acc[8][4];
#pragma unroll
  for (int i = 0; i < 8; ++i)
#pragma unroll
    for (int j = 0; j < 4; ++j)
      acc[i][j] = (f32x4){0.f, 0.f, 0.f, 0.f};

  r5_loop3(X + (size_t)m0 * 1024, 1024, Bg, 1024, 32, lds, acc);

  const int lane = threadIdx.x & 63, w = threadIdx.x >> 6;
  const int r4 = (lane >> 4) * 4;
  const int cn = lane & 15;
  if (n0 < 1024) {
#pragma unroll
    for (int am = 0; am < 8; ++am) {
      const int row = m0 + am * 16 + r4;
#pragma unroll
      for (int fn = 0; fn < 4; ++fn) {
        const int n = n0 + w * 64 + fn * 16 + cn;
        const size_t base = (size_t)row * 1024 + n;
#pragma unroll
        for (int r = 0; r < 4; ++r)
          T[base + (size_t)r * 1024] = (bf16)acc[am][fn][r];
      }
    }
  } else {
    const int b_ = m0 >> 11;
    const int sb = m0 & 2047;
#pragma unroll
    for (int am = 0; am < 8; ++am)
#pragma unroll
      for (int fn = 0; fn < 4; ++fn) {
        const int d  = (n0 - 1024) + w * 64 + fn * 16 + cn;
        const int s0 = sb + am * 16 + r4;
        ushort4 pk;
        pk.x = __builtin_bit_cast(unsigned short, (bf16)acc[am][fn][0]);
        pk.y = __builtin_bit_cast(unsigned short, (bf16)acc[am][fn][1]);
        pk.z = __builtin_bit_cast(unsigned short, (bf16)acc[am][fn][2]);
        pk.w = __builtin_bit_cast(unsigned short, (bf16)acc[am][fn][3]);
        *(ushort4*)(VT + ((size_t)b_ * DOUT + d) * SS + s0) = pk;
      }
  }
}

// ---- scores = T.X^T, fused exp: causal mask + exp(s*scale) + row-sum -------
// Hybrid tail-balanced work-list (576 blocks = per-XCD {64 full r5h + 8 thin
// r5q halves of 4 tiles}).
__global__ __launch_bounds__(256, 3) void k_gemm_qk(const bf16* __restrict__ T,
                                                    const bf16* __restrict__ XB,
                                                    bf16* __restrict__ E,
                                                    float* __restrict__ RS) {
  __shared__ __align__(16) char lds[49152];
  const int c  = blockIdx.x & 7;          // XCD
  const int li = blockIdx.x >> 3;         // 0..71 within XCD chunk
  const bool full = (li < 64);
  const int gt = full ? (c * 68 + li) : (c * 68 + 64 + ((li - 64) >> 1));
  const int nh = full ? 0 : ((li - 64) & 1);

  const int b = gt / 136;
  int r = gt % 136;
  int i = 0;
  for (;;) { const int cnt = i + 1; if (r < cnt) break; r -= cnt; ++i; }
  const int m0 = i * 128;

  bf16* Eb = E + (size_t)b * SS * SS;
  float* RSb = RS + (size_t)b * SS;
  const float scale = 0.03125f;  // 1/sqrt(1024)
  const int lane = threadIdx.x & 63, wid = threadIdx.x >> 6;
  const int wr = wid >> 1, wc = wid & 1;
  const int r4 = (lane >> 4) * 4, cn = lane & 15;

  float rsum[4][4];
#pragma unroll
  for (int fm = 0; fm < 4; ++fm)
#pragma unroll
    for (int rr = 0; rr < 4; ++rr) rsum[fm][rr] = 0.f;

  if (full) {
    const int n0 = r * 128;
    f32x4 acc[4][4];
    acc_zero4(acc);
    r5h_loop3(T  + ((size_t)b * SS + m0) * 1024, 1024,
              XB + ((size_t)b * SS + n0) * 1024, 1024, 32, lds, acc);
#pragma unroll
    for (int fm = 0; fm < 4; ++fm)
#pragma unroll
      for (int fn = 0; fn < 4; ++fn) {
        const int n = n0 + wc * 64 + fn * 16 + cn;
        const int rowb = m0 + wr * 64 + fm * 16 + r4;
        const size_t bofs = (size_t)rowb * SS + n;
#pragma unroll
        for (int rr = 0; rr < 4; ++rr) {
          const float e = (n <= rowb + rr) ? __expf(acc[fm][fn][rr] * scale) : 0.f;
          Eb[bofs + (size_t)rr * SS] = (bf16)e;
          rsum[fm][rr] += e;
        }
      }
  } else {
    const int n0 = r * 128 + nh * 64;
    f32x4 acc[4][2];
#pragma unroll
    for (int ii = 0; ii < 4; ++ii)
#pragma unroll
      for (int jj = 0; jj < 2; ++jj)
        acc[ii][jj] = (f32x4){0.f, 0.f, 0.f, 0.f};
    r5q_loop3(T  + ((size_t)b * SS + m0) * 1024, 1024,
              XB + ((size_t)b * SS + n0) * 1024, 1024, 32, lds, acc);
#pragma unroll
    for (int fm = 0; fm < 4; ++fm)
#pragma unroll
      for (int fn = 0; fn < 2; ++fn) {
        const int n = n0 + wc * 32 + fn * 16 + cn;
        const int rowb = m0 + wr * 64 + fm * 16 + r4;
        const size_t bofs = (size_t)rowb * SS + n;
#pragma unroll
        for (int rr = 0; rr < 4; ++rr) {
          const float e = (n <= rowb + rr) ? __expf(acc[fm][fn][rr] * scale) : 0.f;
          Eb[bofs + (size_t)rr * SS] = (bf16)e;
          rsum[fm][rr] += e;
        }
      }
  }

  // reduce over the 16 cn-lanes (same row group: lane>>4 invariant under xor<16)
#pragma unroll
  for (int fm = 0; fm < 4; ++fm)
#pragma unroll
    for (int rr = 0; rr < 4; ++rr) {
      float s = rsum[fm][rr];
      s += __shfl_xor(s, 1);
      s += __shfl_xor(s, 2);
      s += __shfl_xor(s, 4);
      s += __shfl_xor(s, 8);
      if (cn == 0)
        atomicAdd(&RSb[m0 + wr * 64 + fm * 16 + r4 + rr], s);
    }
}

// ---------------- PV: r5h3, anti-correlated balance (512 blocks) ------------
// Consumes unnormalized E; divides by RS[row] in epilogue.
// Same-j blocks land on one XCD by construction (bid mod 8 = j) -> VT panel
// reuse is XCD-local; (i, 15-i) pairing balances per-CU work at 68 K-steps.
__global__ __launch_bounds__(256, 3) void k_gemm_pv(const bf16* __restrict__ P,
                                                    const bf16* __restrict__ VT,
                                                    const float* __restrict__ RS,
                                                    float* __restrict__ Out) {
  __shared__ __align__(16) char lds[49152];
  const int wfl = blockIdx.x;
  const int h = wfl >> 8;
  const int r = wfl & 255;
  const int b = r >> 6;
  const int t = r & 63;
  const int ip = t >> 3;
  const int j = t & 7;
  const int i = h ? (15 - ip) : ip;
  const int m0 = i * 128, n0 = j * 128;
  const int nt = 4 * (i + 1);     // s-tiles [0, (i+1)*128)

  f32x4 acc[4][4];
  acc_zero4(acc);
  r5h_loop3(P  + (size_t)b * SS * SS   + (size_t)m0 * SS, SS,
            VT + (size_t)b * DOUT * SS + (size_t)n0 * SS, SS,
            nt, lds, acc);

  float* Ob = Out + (size_t)b * SS * DOUT;
  const float* RSb = RS + (size_t)b * SS;
  const int lane = threadIdx.x & 63, wid = threadIdx.x >> 6;
  const int wr = wid >> 1, wc = wid & 1;
  const int r4 = (lane >> 4) * 4, cn = lane & 15;
#pragma unroll
  for (int fm = 0; fm < 4; ++fm) {
    const int rowb = m0 + wr * 64 + fm * 16 + r4;
    const float4 rs4 = *(const float4*)(RSb + rowb);
    float inv[4];
    inv[0] = 1.0f / rs4.x; inv[1] = 1.0f / rs4.y;
    inv[2] = 1.0f / rs4.z; inv[3] = 1.0f / rs4.w;
#pragma unroll
    for (int fn = 0; fn < 4; ++fn) {
      const int n = n0 + wc * 64 + fn * 16 + cn;
      const size_t bofs = (size_t)rowb * DOUT + n;
#pragma unroll
      for (int rr = 0; rr < 4; ++rr)
        Ob[bofs + (size_t)rr * DOUT] = acc[fm][fn][rr] * inv[rr];
    }
  }
}

// ---------------- launch ----------------
extern "C" void kernel_launch(void* const* d_in, const int* in_sizes, int n_in,
                              void* d_out, int out_size, void* d_ws, size_t ws_size,
                              hipStream_t stream) {
  const float* x  = (const float*)d_in[0];
  const float* Wq = (const float*)d_in[1];
  const float* Wk = (const float*)d_in[2];
  const float* Wv = (const float*)d_in[3];
  float* out = (float*)d_out;
  char* ws = (char*)d_ws;

  bf16*  T   = (bf16*)(ws);                        // 16 MB [8192][1024]  X*M
  bf16*  VT  = (bf16*)(ws + ((size_t)16 << 20));   // 16 MB [4][1024][2048]
  bf16*  E   = (bf16*)(ws + ((size_t)32 << 20));   // 32 MB unnorm exp scores
  float* MTp = (float*)(ws + ((size_t)32 << 20));  // 16 MB (aliases E; dead before qk)
  bf16*  XB  = (bf16*)(ws + ((size_t)64 << 20));   // 16 MB (live through qk!)
  bf16*  WTv = (bf16*)(ws + ((size_t)80 << 20));   //  2 MB transposed bf16 Wv
  bf16*  MT  = (bf16*)(ws + ((size_t)82 << 20));   //  2 MB M^T = Wk.Wq^T (bf16)
  float* RS  = (float*)(ws + ((size_t)84 << 20));  // 32 KB row sums [4][2048]

  k_prep<<<5377, 256, 0, stream>>>(x, XB, Wq, Wk, Wv, WTv, MTp, RS);
  k_mtred<<<512, 256, 0, stream>>>(MTp, MT);
  k_tv<<<512, 256, 0, stream>>>(XB, MT, WTv, T, VT);
  k_gemm_qk<<<576, 256, 0, stream>>>(T, XB, E, RS);
  k_gemm_pv<<<512, 256, 0, stream>>>(E, VT, RS, out);
}

// Round 20
// 121.669 us; speedup vs baseline: 1.0335x; 1.0256x over previous
//
#include <hip/hip_runtime.h>
#include <hip/hip_bf16.h>
#include <stdint.h>

typedef __bf16 bf16;
typedef bf16 bf16x8 __attribute__((ext_vector_type(8)));
typedef float f32x4 __attribute__((ext_vector_type(4)));

#define NB   4
#define SS   2048
#define DI   1024
#define DOUT 1024

__device__ __forceinline__ void gload_lds16(const void* g, void* l) {
  __builtin_amdgcn_global_load_lds(
      (const __attribute__((address_space(1))) void*)g,
      (__attribute__((address_space(3))) void*)l, 16, 0, 0);
}

#define BARX  { __builtin_amdgcn_s_barrier(); __builtin_amdgcn_sched_barrier(0); }
#define VMW12 asm volatile("s_waitcnt vmcnt(12)" ::: "memory")
#define VMW8  asm volatile("s_waitcnt vmcnt(8)"  ::: "memory")
#define VMW6  asm volatile("s_waitcnt vmcnt(6)"  ::: "memory")
#define VMW4  asm volatile("s_waitcnt vmcnt(4)"  ::: "memory")
#define VMW3  asm volatile("s_waitcnt vmcnt(3)"  ::: "memory")
#define VMW0  asm volatile("s_waitcnt vmcnt(0)"  ::: "memory")

__device__ __forceinline__ bf16x8 cvt8(float4 a, float4 b) {
  bf16x8 v;
  v[0] = (bf16)a.x; v[1] = (bf16)a.y; v[2] = (bf16)a.z; v[3] = (bf16)a.w;
  v[4] = (bf16)b.x; v[5] = (bf16)b.y; v[6] = (bf16)b.z; v[7] = (bf16)b.w;
  return v;
}

// ------- r5h_3: 128x128 tile, BK=32, TRIPLE-buffer (16KB x3), depth-2 -------
// 4 loads/tile -> 12 in flight; vmcnt(8) retires tile t.
// acc[fm][fn]: row = m0 + wr*64 + fm*16 + (lane>>4)*4 + r;
//              col = n0 + wc*64 + fn*16 + (lane&15)
__device__ __forceinline__ void r5h_loop3(
    const bf16* __restrict__ Ag, int lda,
    const bf16* __restrict__ Bg, int ldb,
    int nt, char* lds, f32x4 (&acc)[4][4])
{
  const int tid = threadIdx.x, lane = tid & 63, wid = tid >> 6;
  const int wr = wid >> 1, wc = wid & 1;
  const int g    = (tid & 3) ^ ((tid >> 3) & 3);
  const int srow = tid >> 2;
  const int l15  = lane & 15, lg = lane >> 4;
  const int aoff = l15 * 64 + ((lg ^ ((l15 >> 1) & 3)) << 4);

  auto STG = [&](int t, int p) {
    char* Ab = lds + p * 16384;
    char* Bb = lds + p * 16384 + 8192;
#pragma unroll
    for (int i = 0; i < 2; ++i) {
      gload_lds16(Ag + (size_t)(i * 64 + srow) * lda + t * 32 + g * 8,
                  Ab + i * 4096 + tid * 16);
      gload_lds16(Bg + (size_t)(i * 64 + srow) * ldb + t * 32 + g * 8,
                  Bb + i * 4096 + tid * 16);
    }
  };

  auto CMP = [&](int p) {
    const char* Ab = lds + p * 16384 + wr * 4096;
    const char* Bb = lds + p * 16384 + 8192 + wc * 4096;
    bf16x8 a[4], bq[4];
#pragma unroll
    for (int fm = 0; fm < 4; ++fm) a[fm] = *(const bf16x8*)(Ab + fm * 1024 + aoff);
#pragma unroll
    for (int fn = 0; fn < 4; ++fn) bq[fn] = *(const bf16x8*)(Bb + fn * 1024 + aoff);
    __builtin_amdgcn_s_setprio(1);
#pragma unroll
    for (int fm = 0; fm < 4; ++fm)
#pragma unroll
      for (int fn = 0; fn < 4; ++fn)
        acc[fm][fn] = __builtin_amdgcn_mfma_f32_16x16x32_bf16(
            a[fm], bq[fn], acc[fm][fn], 0, 0, 0);
    __builtin_amdgcn_s_setprio(0);
  };

  STG(0, 0);
  STG(1, 1);
  int pw = 2, pr = 0;
  for (int t = 0; t < nt - 2; ++t) {
    STG(t + 2, pw);
    VMW8;                  // 12 in flight -> retire tile t's 4
    BARX;
    CMP(pr);
    BARX;
    pw = (pw == 2) ? 0 : pw + 1;
    pr = (pr == 2) ? 0 : pr + 1;
  }
  VMW4; BARX; CMP(pr); BARX;   // 8 in flight -> retire tile nt-2's 4
  pr = (pr == 2) ? 0 : pr + 1;
  VMW0; BARX; CMP(pr);
}

// ------- r5q_3: 128x64 tile, BK=32, TRIPLE-buffer (12KB x3), depth-2 --------
// Thin-N tail-balancer (verified r14). A-staging identical to r5h; B = one
// 4KB load/tile. 3 loads/tile -> 9 in flight; vmcnt(6) retires tile t.
// acc[fm][fn]: row = m0 + wr*64 + fm*16 + r4 + rr; col = n0 + wc*32 + fn*16 + cn
__device__ __forceinline__ void r5q_loop3(
    const bf16* __restrict__ Ag, int lda,
    const bf16* __restrict__ Bg, int ldb,
    int nt, char* lds, f32x4 (&acc)[4][2])
{
  const int tid = threadIdx.x, lane = tid & 63, wid = tid >> 6;
  const int wr = wid >> 1, wc = wid & 1;
  const int g    = (tid & 3) ^ ((tid >> 3) & 3);
  const int srow = tid >> 2;
  const int l15  = lane & 15, lg = lane >> 4;
  const int aoff = l15 * 64 + ((lg ^ ((l15 >> 1) & 3)) << 4);

  auto STG = [&](int t, int p) {
    char* Ab = lds + p * 12288;
    char* Bb = lds + p * 12288 + 8192;
#pragma unroll
    for (int i = 0; i < 2; ++i)
      gload_lds16(Ag + (size_t)(i * 64 + srow) * lda + t * 32 + g * 8,
                  Ab + i * 4096 + tid * 16);
    gload_lds16(Bg + (size_t)srow * ldb + t * 32 + g * 8, Bb + tid * 16);
  };

  auto CMP = [&](int p) {
    const char* Ab = lds + p * 12288 + wr * 4096;
    const char* Bb = lds + p * 12288 + 8192 + wc * 2048;
    bf16x8 a[4], bq[2];
#pragma unroll
    for (int fm = 0; fm < 4; ++fm) a[fm] = *(const bf16x8*)(Ab + fm * 1024 + aoff);
#pragma unroll
    for (int fn = 0; fn < 2; ++fn) bq[fn] = *(const bf16x8*)(Bb + fn * 1024 + aoff);
    __builtin_amdgcn_s_setprio(1);
#pragma unroll
    for (int fm = 0; fm < 4; ++fm)
#pragma unroll
      for (int fn = 0; fn < 2; ++fn)
        acc[fm][fn] = __builtin_amdgcn_mfma_f32_16x16x32_bf16(
            a[fm], bq[fn], acc[fm][fn], 0, 0, 0);
    __builtin_amdgcn_s_setprio(0);
  };

  STG(0, 0);
  STG(1, 1);
  int pw = 2, pr = 0;
  for (int t = 0; t < nt - 2; ++t) {
    STG(t + 2, pw);
    VMW6;                  // 9 in flight -> retire tile t's 3
    BARX;
    CMP(pr);
    BARX;
    pw = (pw == 2) ? 0 : pw + 1;
    pr = (pr == 2) ? 0 : pr + 1;
  }
  VMW3; BARX; CMP(pr); BARX;   // 6 in flight -> retire tile nt-2's 3
  pr = (pr == 2) ? 0 : pr + 1;
  VMW0; BARX; CMP(pr);
}

__device__ __forceinline__ void acc_zero4(f32x4 (&acc)[4][4]) {
#pragma unroll
  for (int i = 0; i < 4; ++i)
#pragma unroll
    for (int j = 0; j < 4; ++j)
      acc[i][j] = (f32x4){0.f, 0.f, 0.f, 0.f};
}

// ---- prep: MT split-4 partials | x cast | Wv transpose | RS zero -----------
__global__ __launch_bounds__(256) void k_prep(const float* __restrict__ x,
                                              bf16* __restrict__ xb,
                                              const float* __restrict__ Wq,
                                              const float* __restrict__ Wk,
                                              const float* __restrict__ Wv,
                                              bf16* __restrict__ WTv,
                                              float* __restrict__ MTp,
                                              float* __restrict__ RS) {
  __shared__ __align__(16) char lds[16384];
  const int bid = blockIdx.x;
  const int tid = threadIdx.x;

  if (bid < 256) {
    // ---- MT partial: MTp[s][j'][j] = sum_{d in slice s} Wk[j'][d]*Wq[j][d] --
    const int tile = bid >> 2, s = bid & 3;
    const int m0 = (tile >> 3) * 128, n0 = (tile & 7) * 128;
    const int k0 = s * 256;
    const int lane = tid & 63, wid = tid >> 6;
    const int wr = wid >> 1, wc = wid & 1;
    const int g    = (tid & 3) ^ ((tid >> 3) & 3);
    const int srow = tid >> 2;
    const int l15  = lane & 15, lg = lane >> 4;
    const int aoff = l15 * 64 + ((lg ^ ((l15 >> 1) & 3)) << 4);

    const float* ap0 = Wk + (size_t)(m0 + srow) * DI + k0 + g * 8;
    const float* ap1 = Wk + (size_t)(m0 + 64 + srow) * DI + k0 + g * 8;
    const float* bp0 = Wq + (size_t)(n0 + srow) * DI + k0 + g * 8;
    const float* bp1 = Wq + (size_t)(n0 + 64 + srow) * DI + k0 + g * 8;

    f32x4 acc[4][4];
    acc_zero4(acc);

    // preload step 0
    float4 A00 = *(const float4*)(ap0), A01 = *(const float4*)(ap0 + 4);
    float4 A10 = *(const float4*)(ap1), A11 = *(const float4*)(ap1 + 4);
    float4 B00 = *(const float4*)(bp0), B01 = *(const float4*)(bp0 + 4);
    float4 B10 = *(const float4*)(bp1), B11 = *(const float4*)(bp1 + 4);

    for (int t = 0; t < 8; ++t) {
      float4 nA00, nA01, nA10, nA11, nB00, nB01, nB10, nB11;
      if (t < 7) {               // issue next-step loads early (hide under MFMA)
        const int o = (t + 1) * 32;
        nA00 = *(const float4*)(ap0 + o); nA01 = *(const float4*)(ap0 + o + 4);
        nA10 = *(const float4*)(ap1 + o); nA11 = *(const float4*)(ap1 + o + 4);
        nB00 = *(const float4*)(bp0 + o); nB01 = *(const float4*)(bp0 + o + 4);
        nB10 = *(const float4*)(bp1 + o); nB11 = *(const float4*)(bp1 + o + 4);
      }
      // stage current step (reg -> cvt -> LDS), r5h layout
      *(bf16x8*)(lds + tid * 16)         = cvt8(A00, A01);
      *(bf16x8*)(lds + 4096 + tid * 16)  = cvt8(A10, A11);
      *(bf16x8*)(lds + 8192 + tid * 16)  = cvt8(B00, B01);
      *(bf16x8*)(lds + 12288 + tid * 16) = cvt8(B10, B11);
      __syncthreads();
      {
        const char* Ab = lds + wr * 4096;
        const char* Bb = lds + 8192 + wc * 4096;
        bf16x8 a[4], bq[4];
#pragma unroll
        for (int fm = 0; fm < 4; ++fm) a[fm] = *(const bf16x8*)(Ab + fm * 1024 + aoff);
#pragma unroll
        for (int fn = 0; fn < 4; ++fn) bq[fn] = *(const bf16x8*)(Bb + fn * 1024 + aoff);
#pragma unroll
        for (int fm = 0; fm < 4; ++fm)
#pragma unroll
          for (int fn = 0; fn < 4; ++fn)
            acc[fm][fn] = __builtin_amdgcn_mfma_f32_16x16x32_bf16(
                a[fm], bq[fn], acc[fm][fn], 0, 0, 0);
      }
      __syncthreads();
      A00 = nA00; A01 = nA01; A10 = nA10; A11 = nA11;
      B00 = nB00; B01 = nB01; B10 = nB10; B11 = nB11;
    }

    float* MPs = MTp + (size_t)s * (1024 * 1024);
    const int r4 = (lane >> 4) * 4, cn = lane & 15;
#pragma unroll
    for (int fm = 0; fm < 4; ++fm)
#pragma unroll
      for (int fn = 0; fn < 4; ++fn) {
        const int rowb = m0 + wr * 64 + fm * 16 + r4;
        const int col  = n0 + wc * 64 + fn * 16 + cn;
#pragma unroll
        for (int rr = 0; rr < 4; ++rr)
          MPs[(size_t)(rowb + rr) * 1024 + col] = acc[fm][fn][rr];
      }
  } else if (bid < 4352) {
    // ---- x cast ----
    const size_t i = ((size_t)(bid - 256) * 256 + tid) * 8;
    const float4 a = *(const float4*)(x + i);
    const float4 c = *(const float4*)(x + i + 4);
    *(bf16x8*)(xb + i) = cvt8(a, c);
  } else if (bid < 5376) {
    // ---- Wv transpose-cast: 32x32 tile ----
    float (*t)[33] = (float (*)[33])lds;
    const int tt = bid - 4352;
    const int c0 = (tt & 31) * 32, k0 = (tt >> 5) * 32;
    const int tx = tid & 31, ty = tid >> 5;   // 32 x 8
#pragma unroll
    for (int i = 0; i < 4; ++i)
      t[ty + 8 * i][tx] = Wv[(size_t)(k0 + ty + 8 * i) * DI + c0 + tx];
    __syncthreads();
#pragma unroll
    for (int i = 0; i < 4; ++i)
      WTv[(size_t)(c0 + ty + 8 * i) * DI + k0 + tx] = (bf16)t[tx][ty + 8 * i];
  } else {
    // ---- RS zero: 8192 f32 = 32 f32/thread ----
    float4 z = {0.f, 0.f, 0.f, 0.f};
#pragma unroll
    for (int i = 0; i < 8; ++i)
      *(float4*)(RS + (size_t)tid * 32 + i * 4) = z;
  }
}

// ---- mtred: reduce 4 MTp planes (f32) -> MT (bf16), 512 blocks -------------
__global__ __launch_bounds__(256) void k_mtred(const float* __restrict__ MTp,
                                               bf16* __restrict__ MT) {
  const size_t i = ((size_t)blockIdx.x * 256 + threadIdx.x) * 8;
  float4 a = *(const float4*)(MTp + i);
  float4 b = *(const float4*)(MTp + i + 4);
#pragma unroll
  for (int s = 1; s < 4; ++s) {
    const float* p = MTp + (size_t)s * (1024 * 1024) + i;
    const float4 c = *(const float4*)p;
    const float4 d = *(const float4*)(p + 4);
    a.x += c.x; a.y += c.y; a.z += c.z; a.w += c.w;
    b.x += d.x; b.y += d.y; b.z += d.z; b.w += d.w;
  }
  *(bf16x8*)(MT + i) = cvt8(a, b);
}

// ------- T|V fused: 256x256 4-phase counted-vmcnt + XOR bank-swizzle --------
// r16 retry with the ONE diagnosed fix: r16's 9.4M bank conflicts came from
// 16 lanes reading a 128B-stride column (4 of 8 bank-quads @16-way). Fix per
// G4/rule#21: linear gload_lds dest + inverse-swizzled global SOURCE
// (k-chunk kq ^ (srow8&7)) + swizzled READ (off ^= (l15&7)<<4). Bits 4-6 of
// the read offset are exactly the col16 field (lg*16 + kk*64 <= 112, no
// carries), so the XOR spreads 64 lanes over all 8 bank-quads at the wave
// minimum of 8 -> conflict-free like r5's verified aoff.
// Schedule identical to r16: 512 thr (8 waves 2Mx4N), BK=64, 2x64KB LDS,
// phases {reads||stage -> bar -> MFMA -> bar}, steady-state vmcnt(6).
__global__ __launch_bounds__(512, 2) void k_tv(const bf16* __restrict__ X,
                                               const bf16* __restrict__ MT,
                                               const bf16* __restrict__ WTv,
                                               bf16* __restrict__ T,
                                               bf16* __restrict__ VT) {
  __shared__ __align__(16) char lds[131072];
  const int bid  = blockIdx.x;
  // XCD-aware bijective swizzle: 256 = 8 * 32
  const int wgid = (bid & 7) * 32 + (bid >> 3);
  const int m0 = (wgid >> 3) * 256;
  const int n0 = (wgid & 7) * 256;

  const bf16* Ag = X + (size_t)m0 * 1024;
  const bf16* Bg = (n0 < 1024) ? MT + (size_t)n0 * 1024
                               : WTv + (size_t)(n0 - 1024) * 1024;

  const int tid = threadIdx.x, lane = tid & 63, w = tid >> 6;
  const int wr = w >> 2, wcn = w & 3;
  const int l15 = lane & 15, lg = lane >> 4;
  const int srow8 = tid >> 3, kq = tid & 7;
  const int kqs = kq ^ (srow8 & 7);        // pre-swizzled source col16
  const int swz = (l15 & 7) << 4;          // read-side XOR (bits 4-6)

  // fragment lane offsets in the [256 rows][128B] buffers (pre-XOR)
  const int aBase = wr * 16384 + l15 * 128 + lg * 16;   // A: wr*128 rows
  const int bBase = wcn * 8192 + l15 * 128 + lg * 16;   // B: wcn*64 rows

  // q: 0=A-lo 1=A-hi 2=B-lo 3=B-hi ; dest = uniform + tid*16 (gload_lds rule)
  auto STGH = [&](int t, int q) {
    char* dst = lds + (t & 1) * 65536 + ((q & 2) ? 32768 : 0)
                + ((q & 1) ? 16384 : 0);
    const bf16* src = (q & 2) ? Bg : Ag;
    const int rb = (q & 1) ? 128 : 0;
#pragma unroll
    for (int j = 0; j < 2; ++j)
      gload_lds16(src + (size_t)(rb + j * 64 + srow8) * 1024 + t * 64 + kqs * 8,
                  dst + j * 8192 + tid * 16);
  };

  f32x4 acc[8][4];
#pragma unroll
  for (int i = 0; i < 8; ++i)
#pragma unroll
    for (int j = 0; j < 4; ++j)
      acc[i][j] = (f32x4){0.f, 0.f, 0.f, 0.f};

  // prologue: t0 all 4 halves; t1 Alo, Ahi, Blo (Bhi staged at t0-p0)
  STGH(0, 0); STGH(0, 1); STGH(0, 2); STGH(0, 3);
  STGH(1, 0); STGH(1, 1); STGH(1, 2);

  for (int t = 0; t < 16; ++t) {
    if (t < 15) { VMW6; } else { VMW0; }
    BARX;                                   // buffer t&1 resident (all waves)
    const char* Ab = lds + (t & 1) * 65536;
    const char* Bb = Ab + 32768;
    bf16x8 a[8], b[4], b2[4];

    // ---- p0: fm0-3 x fn0-1 ----
#pragma unroll
    for (int fm = 0; fm < 4; ++fm)
#pragma unroll
      for (int kk = 0; kk < 2; ++kk)
        a[fm * 2 + kk] = *(const bf16x8*)(Ab + ((aBase + fm * 2048 + kk * 64) ^ swz));
#pragma unroll
    for (int fn = 0; fn < 2; ++fn)
#pragma unroll
      for (int kk = 0; kk < 2; ++kk)
        b[fn * 2 + kk] = *(const bf16x8*)(Bb + ((bBase + fn * 2048 + kk * 64) ^ swz));
    if (t + 1 < 16) STGH(t + 1, 3);
    BARX;
    __builtin_amdgcn_s_setprio(1);
#pragma unroll
    for (int fm = 0; fm < 4; ++fm)
#pragma unroll
      for (int fn = 0; fn < 2; ++fn)
#pragma unroll
        for (int kk = 0; kk < 2; ++kk)
          acc[fm][fn] = __builtin_amdgcn_mfma_f32_16x16x32_bf16(
              a[fm * 2 + kk], b[fn * 2 + kk], acc[fm][fn], 0, 0, 0);
    __builtin_amdgcn_s_setprio(0);
    BARX;

    // ---- p1: fm0-3 x fn2-3 (reuse a) ----
#pragma unroll
    for (int fn = 0; fn < 2; ++fn)
#pragma unroll
      for (int kk = 0; kk < 2; ++kk)
        b2[fn * 2 + kk] = *(const bf16x8*)(Bb + ((bBase + 4096 + fn * 2048 + kk * 64) ^ swz));
    BARX;
    __builtin_amdgcn_s_setprio(1);
#pragma unroll
    for (int fm = 0; fm < 4; ++fm)
#pragma unroll
      for (int fn = 0; fn < 2; ++fn)
#pragma unroll
        for (int kk = 0; kk < 2; ++kk)
          acc[fm][2 + fn] = __builtin_amdgcn_mfma_f32_16x16x32_bf16(
              a[fm * 2 + kk], b2[fn * 2 + kk], acc[fm][2 + fn], 0, 0, 0);
    __builtin_amdgcn_s_setprio(0);
    BARX;

    // ---- p2: fm4-7 x fn0-1 (read a2 into a[], reuse b) ----
#pragma unroll
    for (int fm = 0; fm < 4; ++fm)
#pragma unroll
      for (int kk = 0; kk < 2; ++kk)
        a[fm * 2 + kk] = *(const bf16x8*)(Ab + ((aBase + 8192 + fm * 2048 + kk * 64) ^ swz));
    if (t + 2 < 16) STGH(t + 2, 2);
    BARX;
    __builtin_amdgcn_s_setprio(1);
#pragma unroll
    for (int fm = 0; fm < 4; ++fm)
#pragma unroll
      for (int fn = 0; fn < 2; ++fn)
#pragma unroll
        for (int kk = 0; kk < 2; ++kk)
          acc[4 + fm][fn] = __builtin_amdgcn_mfma_f32_16x16x32_bf16(
              a[fm * 2 + kk], b[fn * 2 + kk], acc[4 + fm][fn], 0, 0, 0);
    __builtin_amdgcn_s_setprio(0);
    BARX;

    // ---- p3: fm4-7 x fn2-3 (reuse a2, b2) ----
    if (t + 2 < 16) { STGH(t + 2, 0); STGH(t + 2, 1); }
    BARX;
    __builtin_amdgcn_s_setprio(1);
#pragma unroll
    for (int fm = 0; fm < 4; ++fm)
#pragma unroll
      for (int fn = 0; fn < 2; ++fn)
#pragma unroll
        for (int kk = 0; kk < 2; ++kk)
          acc[4 + fm][2 + fn] = __builtin_amdgcn_mfma_f32_16x16x32_bf16(
              a[fm * 2 + kk], b2[fn * 2 + kk], acc[4 + fm][2 + fn], 0, 0, 0);
    __builtin_amdgcn_s_setprio(0);
    BARX;
  }

  // ---- epilogue (r4/r16-verified mapping) ----
  const int r4 = (lane >> 4) * 4;
  const int cn = lane & 15;
  if (n0 < 1024) {
#pragma unroll
    for (int fm = 0; fm < 8; ++fm) {
      const int row = m0 + wr * 128 + fm * 16 + r4;
#pragma unroll
      for (int fn = 0; fn < 4; ++fn) {
        const int n = n0 + wcn * 64 + fn * 16 + cn;
        const size_t base = (size_t)row * 1024 + n;
#pragma unroll
        for (int r = 0; r < 4; ++r)
          T[base + (size_t)r * 1024] = (bf16)acc[fm][fn][r];
      }
    }
  } else {
    const int b_ = m0 >> 11;
    const int sb = (m0 & 2047) + wr * 128 + r4;
    // fn outer / fm inner: each VT line completes in consecutive stores
#pragma unroll
    for (int fn = 0; fn < 4; ++fn) {
      const int d = (n0 - 1024) + wcn * 64 + fn * 16 + cn;
      bf16* vp = VT + ((size_t)b_ * DOUT + d) * SS;
#pragma unroll
      for (int fm = 0; fm < 8; ++fm) {
        const int s0 = sb + fm * 16;
        ushort4 pk;
        pk.x = __builtin_bit_cast(unsigned short, (bf16)acc[fm][fn][0]);
        pk.y = __builtin_bit_cast(unsigned short, (bf16)acc[fm][fn][1]);
        pk.z = __builtin_bit_cast(unsigned short, (bf16)acc[fm][fn][2]);
        pk.w = __builtin_bit_cast(unsigned short, (bf16)acc[fm][fn][3]);
        *(ushort4*)(vp + s0) = pk;
      }
    }
  }
}

// ---- scores = T.X^T, fused exp: causal mask + exp(s*scale) + row-sum -------
// Hybrid tail-balanced work-list (576 blocks = per-XCD {64 full r5h + 8 thin
// r5q halves of 4 tiles}).
__global__ __launch_bounds__(256, 3) void k_gemm_qk(const bf16* __restrict__ T,
                                                    const bf16* __restrict__ XB,
                                                    bf16* __restrict__ E,
                                                    float* __restrict__ RS) {
  __shared__ __align__(16) char lds[49152];
  const int c  = blockIdx.x & 7;          // XCD
  const int li = blockIdx.x >> 3;         // 0..71 within XCD chunk
  const bool full = (li < 64);
  const int gt = full ? (c * 68 + li) : (c * 68 + 64 + ((li - 64) >> 1));
  const int nh = full ? 0 : ((li - 64) & 1);

  const int b = gt / 136;
  int r = gt % 136;
  int i = 0;
  for (;;) { const int cnt = i + 1; if (r < cnt) break; r -= cnt; ++i; }
  const int m0 = i * 128;

  bf16* Eb = E + (size_t)b * SS * SS;
  float* RSb = RS + (size_t)b * SS;
  const float scale = 0.03125f;  // 1/sqrt(1024)
  const int lane = threadIdx.x & 63, wid = threadIdx.x >> 6;
  const int wr = wid >> 1, wc = wid & 1;
  const int r4 = (lane >> 4) * 4, cn = lane & 15;

  float rsum[4][4];
#pragma unroll
  for (int fm = 0; fm < 4; ++fm)
#pragma unroll
    for (int rr = 0; rr < 4; ++rr) rsum[fm][rr] = 0.f;

  if (full) {
    const int n0 = r * 128;
    f32x4 acc[4][4];
    acc_zero4(acc);
    r5h_loop3(T  + ((size_t)b * SS + m0) * 1024, 1024,
              XB + ((size_t)b * SS + n0) * 1024, 1024, 32, lds, acc);
#pragma unroll
    for (int fm = 0; fm < 4; ++fm)
#pragma unroll
      for (int fn = 0; fn < 4; ++fn) {
        const int n = n0 + wc * 64 + fn * 16 + cn;
        const int rowb = m0 + wr * 64 + fm * 16 + r4;
        const size_t bofs = (size_t)rowb * SS + n;
#pragma unroll
        for (int rr = 0; rr < 4; ++rr) {
          const float e = (n <= rowb + rr) ? __expf(acc[fm][fn][rr] * scale) : 0.f;
          Eb[bofs + (size_t)rr * SS] = (bf16)e;
          rsum[fm][rr] += e;
        }
      }
  } else {
    const int n0 = r * 128 + nh * 64;
    f32x4 acc[4][2];
#pragma unroll
    for (int ii = 0; ii < 4; ++ii)
#pragma unroll
      for (int jj = 0; jj < 2; ++jj)
        acc[ii][jj] = (f32x4){0.f, 0.f, 0.f, 0.f};
    r5q_loop3(T  + ((size_t)b * SS + m0) * 1024, 1024,
              XB + ((size_t)b * SS + n0) * 1024, 1024, 32, lds, acc);
#pragma unroll
    for (int fm = 0; fm < 4; ++fm)
#pragma unroll
      for (int fn = 0; fn < 2; ++fn) {
        const int n = n0 + wc * 32 + fn * 16 + cn;
        const int rowb = m0 + wr * 64 + fm * 16 + r4;
        const size_t bofs = (size_t)rowb * SS + n;
#pragma unroll
        for (int rr = 0; rr < 4; ++rr) {
          const float e = (n <= rowb + rr) ? __expf(acc[fm][fn][rr] * scale) : 0.f;
          Eb[bofs + (size_t)rr * SS] = (bf16)e;
          rsum[fm][rr] += e;
        }
      }
  }

  // reduce over the 16 cn-lanes (same row group: lane>>4 invariant under xor<16)
#pragma unroll
  for (int fm = 0; fm < 4; ++fm)
#pragma unroll
    for (int rr = 0; rr < 4; ++rr) {
      float s = rsum[fm][rr];
      s += __shfl_xor(s, 1);
      s += __shfl_xor(s, 2);
      s += __shfl_xor(s, 4);
      s += __shfl_xor(s, 8);
      if (cn == 0)
        atomicAdd(&RSb[m0 + wr * 64 + fm * 16 + r4 + rr], s);
    }
}

// ---------------- PV: r5h3, anti-correlated balance (512 blocks) ------------
// Consumes unnormalized E; divides by RS[row] in epilogue.
__global__ __launch_bounds__(256, 3) void k_gemm_pv(const bf16* __restrict__ P,
                                                    const bf16* __restrict__ VT,
                                                    const float* __restrict__ RS,
                                                    float* __restrict__ Out) {
  __shared__ __align__(16) char lds[49152];
  const int wfl = blockIdx.x;
  const int h = wfl >> 8;
  const int r = wfl & 255;
  const int b = r >> 6;
  const int t = r & 63;
  const int ip = t >> 3;
  const int j = t & 7;
  const int i = h ? (15 - ip) : ip;
  const int m0 = i * 128, n0 = j * 128;
  const int nt = 4 * (i + 1);     // s-tiles [0, (i+1)*128)

  f32x4 acc[4][4];
  acc_zero4(acc);
  r5h_loop3(P  + (size_t)b * SS * SS   + (size_t)m0 * SS, SS,
            VT + (size_t)b * DOUT * SS + (size_t)n0 * SS, SS,
            nt, lds, acc);

  float* Ob = Out + (size_t)b * SS * DOUT;
  const float* RSb = RS + (size_t)b * SS;
  const int lane = threadIdx.x & 63, wid = threadIdx.x >> 6;
  const int wr = wid >> 1, wc = wid & 1;
  const int r4 = (lane >> 4) * 4, cn = lane & 15;
#pragma unroll
  for (int fm = 0; fm < 4; ++fm) {
    const int rowb = m0 + wr * 64 + fm * 16 + r4;
    const float4 rs4 = *(const float4*)(RSb + rowb);
    float inv[4];
    inv[0] = 1.0f / rs4.x; inv[1] = 1.0f / rs4.y;
    inv[2] = 1.0f / rs4.z; inv[3] = 1.0f / rs4.w;
#pragma unroll
    for (int fn = 0; fn < 4; ++fn) {
      const int n = n0 + wc * 64 + fn * 16 + cn;
      const size_t bofs = (size_t)rowb * DOUT + n;
#pragma unroll
      for (int rr = 0; rr < 4; ++rr)
        Ob[bofs + (size_t)rr * DOUT] = acc[fm][fn][rr] * inv[rr];
    }
  }
}

// ---------------- launch ----------------
extern "C" void kernel_launch(void* const* d_in, const int* in_sizes, int n_in,
                              void* d_out, int out_size, void* d_ws, size_t ws_size,
                              hipStream_t stream) {
  const float* x  = (const float*)d_in[0];
  const float* Wq = (const float*)d_in[1];
  const float* Wk = (const float*)d_in[2];
  const float* Wv = (const float*)d_in[3];
  float* out = (float*)d_out;
  char* ws = (char*)d_ws;

  bf16*  T   = (bf16*)(ws);                        // 16 MB [8192][1024]  X*M
  bf16*  VT  = (bf16*)(ws + ((size_t)16 << 20));   // 16 MB [4][1024][2048]
  bf16*  E   = (bf16*)(ws + ((size_t)32 << 20));   // 32 MB unnorm exp scores
  float* MTp = (float*)(ws + ((size_t)32 << 20));  // 16 MB (aliases E; dead before qk)
  bf16*  XB  = (bf16*)(ws + ((size_t)64 << 20));   // 16 MB (live through qk!)
  bf16*  WTv = (bf16*)(ws + ((size_t)80 << 20));   //  2 MB transposed bf16 Wv
  bf16*  MT  = (bf16*)(ws + ((size_t)82 << 20));   //  2 MB M^T = Wk.Wq^T (bf16)
  float* RS  = (float*)(ws + ((size_t)84 << 20));  // 32 KB row sums [4][2048]

  k_prep<<<5377, 256, 0, stream>>>(x, XB, Wq, Wk, Wv, WTv, MTp, RS);
  k_mtred<<<512, 256, 0, stream>>>(MTp, MT);
  k_tv<<<256, 512, 0, stream>>>(XB, MT, WTv, T, VT);
  k_gemm_qk<<<576, 256, 0, stream>>>(T, XB, E, RS);
  k_gemm_pv<<<512, 256, 0, stream>>>(E, VT, RS, out);
}

// Round 21
// 121.582 us; speedup vs baseline: 1.0343x; 1.0007x over previous
//
#include <hip/hip_runtime.h>
#include <hip/hip_bf16.h>
#include <stdint.h>

typedef __bf16 bf16;
typedef bf16 bf16x8 __attribute__((ext_vector_type(8)));
typedef float f32x4 __attribute__((ext_vector_type(4)));

#define NB   4
#define SS   2048
#define DI   1024
#define DOUT 1024

__device__ __forceinline__ void gload_lds16(const void* g, void* l) {
  __builtin_amdgcn_global_load_lds(
      (const __attribute__((address_space(1))) void*)g,
      (__attribute__((address_space(3))) void*)l, 16, 0, 0);
}

#define BARX  { __builtin_amdgcn_s_barrier(); __builtin_amdgcn_sched_barrier(0); }
#define VMW8  asm volatile("s_waitcnt vmcnt(8)"  ::: "memory")
#define VMW6  asm volatile("s_waitcnt vmcnt(6)"  ::: "memory")
#define VMW4  asm volatile("s_waitcnt vmcnt(4)"  ::: "memory")
#define VMW3  asm volatile("s_waitcnt vmcnt(3)"  ::: "memory")
#define VMW0  asm volatile("s_waitcnt vmcnt(0)"  ::: "memory")

__device__ __forceinline__ bf16x8 cvt8(float4 a, float4 b) {
  bf16x8 v;
  v[0] = (bf16)a.x; v[1] = (bf16)a.y; v[2] = (bf16)a.z; v[3] = (bf16)a.w;
  v[4] = (bf16)b.x; v[5] = (bf16)b.y; v[6] = (bf16)b.z; v[7] = (bf16)b.w;
  return v;
}

// ------- r5h_3: 128x128 tile, BK=32, TRIPLE-buffer (16KB x3), depth-2 -------
// 4 loads/tile -> 12 in flight; vmcnt(8) retires tile t.
// acc[fm][fn]: row = m0 + wr*64 + fm*16 + (lane>>4)*4 + r;
//              col = n0 + wc*64 + fn*16 + (lane&15)
__device__ __forceinline__ void r5h_loop3(
    const bf16* __restrict__ Ag, int lda,
    const bf16* __restrict__ Bg, int ldb,
    int nt, char* lds, f32x4 (&acc)[4][4])
{
  const int tid = threadIdx.x, lane = tid & 63, wid = tid >> 6;
  const int wr = wid >> 1, wc = wid & 1;
  const int g    = (tid & 3) ^ ((tid >> 3) & 3);
  const int srow = tid >> 2;
  const int l15  = lane & 15, lg = lane >> 4;
  const int aoff = l15 * 64 + ((lg ^ ((l15 >> 1) & 3)) << 4);

  auto STG = [&](int t, int p) {
    char* Ab = lds + p * 16384;
    char* Bb = lds + p * 16384 + 8192;
#pragma unroll
    for (int i = 0; i < 2; ++i) {
      gload_lds16(Ag + (size_t)(i * 64 + srow) * lda + t * 32 + g * 8,
                  Ab + i * 4096 + tid * 16);
      gload_lds16(Bg + (size_t)(i * 64 + srow) * ldb + t * 32 + g * 8,
                  Bb + i * 4096 + tid * 16);
    }
  };

  auto CMP = [&](int p) {
    const char* Ab = lds + p * 16384 + wr * 4096;
    const char* Bb = lds + p * 16384 + 8192 + wc * 4096;
    bf16x8 a[4], bq[4];
#pragma unroll
    for (int fm = 0; fm < 4; ++fm) a[fm] = *(const bf16x8*)(Ab + fm * 1024 + aoff);
#pragma unroll
    for (int fn = 0; fn < 4; ++fn) bq[fn] = *(const bf16x8*)(Bb + fn * 1024 + aoff);
    __builtin_amdgcn_s_setprio(1);
#pragma unroll
    for (int fm = 0; fm < 4; ++fm)
#pragma unroll
      for (int fn = 0; fn < 4; ++fn)
        acc[fm][fn] = __builtin_amdgcn_mfma_f32_16x16x32_bf16(
            a[fm], bq[fn], acc[fm][fn], 0, 0, 0);
    __builtin_amdgcn_s_setprio(0);
  };

  STG(0, 0);
  STG(1, 1);
  int pw = 2, pr = 0;
  for (int t = 0; t < nt - 2; ++t) {
    STG(t + 2, pw);
    VMW8;                  // 12 in flight -> retire tile t's 4
    BARX;
    CMP(pr);
    BARX;
    pw = (pw == 2) ? 0 : pw + 1;
    pr = (pr == 2) ? 0 : pr + 1;
  }
  VMW4; BARX; CMP(pr); BARX;   // 8 in flight -> retire tile nt-2's 4
  pr = (pr == 2) ? 0 : pr + 1;
  VMW0; BARX; CMP(pr);
}

// ------- r5q_3: 128x64 tile, BK=32, TRIPLE-buffer (12KB x3), depth-2 --------
// Thin-N tail-balancer (verified r14). A-staging identical to r5h; B = one
// 4KB load/tile. 3 loads/tile -> 9 in flight; vmcnt(6) retires tile t.
// acc[fm][fn]: row = m0 + wr*64 + fm*16 + r4 + rr; col = n0 + wc*32 + fn*16 + cn
__device__ __forceinline__ void r5q_loop3(
    const bf16* __restrict__ Ag, int lda,
    const bf16* __restrict__ Bg, int ldb,
    int nt, char* lds, f32x4 (&acc)[4][2])
{
  const int tid = threadIdx.x, lane = tid & 63, wid = tid >> 6;
  const int wr = wid >> 1, wc = wid & 1;
  const int g    = (tid & 3) ^ ((tid >> 3) & 3);
  const int srow = tid >> 2;
  const int l15  = lane & 15, lg = lane >> 4;
  const int aoff = l15 * 64 + ((lg ^ ((l15 >> 1) & 3)) << 4);

  auto STG = [&](int t, int p) {
    char* Ab = lds + p * 12288;
    char* Bb = lds + p * 12288 + 8192;
#pragma unroll
    for (int i = 0; i < 2; ++i)
      gload_lds16(Ag + (size_t)(i * 64 + srow) * lda + t * 32 + g * 8,
                  Ab + i * 4096 + tid * 16);
    gload_lds16(Bg + (size_t)srow * ldb + t * 32 + g * 8, Bb + tid * 16);
  };

  auto CMP = [&](int p) {
    const char* Ab = lds + p * 12288 + wr * 4096;
    const char* Bb = lds + p * 12288 + 8192 + wc * 2048;
    bf16x8 a[4], bq[2];
#pragma unroll
    for (int fm = 0; fm < 4; ++fm) a[fm] = *(const bf16x8*)(Ab + fm * 1024 + aoff);
#pragma unroll
    for (int fn = 0; fn < 2; ++fn) bq[fn] = *(const bf16x8*)(Bb + fn * 1024 + aoff);
    __builtin_amdgcn_s_setprio(1);
#pragma unroll
    for (int fm = 0; fm < 4; ++fm)
#pragma unroll
      for (int fn = 0; fn < 2; ++fn)
        acc[fm][fn] = __builtin_amdgcn_mfma_f32_16x16x32_bf16(
            a[fm], bq[fn], acc[fm][fn], 0, 0, 0);
    __builtin_amdgcn_s_setprio(0);
  };

  STG(0, 0);
  STG(1, 1);
  int pw = 2, pr = 0;
  for (int t = 0; t < nt - 2; ++t) {
    STG(t + 2, pw);
    VMW6;                  // 9 in flight -> retire tile t's 3
    BARX;
    CMP(pr);
    BARX;
    pw = (pw == 2) ? 0 : pw + 1;
    pr = (pr == 2) ? 0 : pr + 1;
  }
  VMW3; BARX; CMP(pr); BARX;   // 6 in flight -> retire tile nt-2's 3
  pr = (pr == 2) ? 0 : pr + 1;
  VMW0; BARX; CMP(pr);
}

__device__ __forceinline__ void acc_zero4(f32x4 (&acc)[4][4]) {
#pragma unroll
  for (int i = 0; i < 4; ++i)
#pragma unroll
    for (int j = 0; j < 4; ++j)
      acc[i][j] = (f32x4){0.f, 0.f, 0.f, 0.f};
}

// ---- prep: MT split-4 partials | x cast | Wv transpose | RS zero -----------
__global__ __launch_bounds__(256) void k_prep(const float* __restrict__ x,
                                              bf16* __restrict__ xb,
                                              const float* __restrict__ Wq,
                                              const float* __restrict__ Wk,
                                              const float* __restrict__ Wv,
                                              bf16* __restrict__ WTv,
                                              float* __restrict__ MTp,
                                              float* __restrict__ RS) {
  __shared__ __align__(16) char lds[16384];
  const int bid = blockIdx.x;
  const int tid = threadIdx.x;

  if (bid < 256) {
    // ---- MT partial: MTp[s][j'][j] = sum_{d in slice s} Wk[j'][d]*Wq[j][d] --
    const int tile = bid >> 2, s = bid & 3;
    const int m0 = (tile >> 3) * 128, n0 = (tile & 7) * 128;
    const int k0 = s * 256;
    const int lane = tid & 63, wid = tid >> 6;
    const int wr = wid >> 1, wc = wid & 1;
    const int g    = (tid & 3) ^ ((tid >> 3) & 3);
    const int srow = tid >> 2;
    const int l15  = lane & 15, lg = lane >> 4;
    const int aoff = l15 * 64 + ((lg ^ ((l15 >> 1) & 3)) << 4);

    const float* ap0 = Wk + (size_t)(m0 + srow) * DI + k0 + g * 8;
    const float* ap1 = Wk + (size_t)(m0 + 64 + srow) * DI + k0 + g * 8;
    const float* bp0 = Wq + (size_t)(n0 + srow) * DI + k0 + g * 8;
    const float* bp1 = Wq + (size_t)(n0 + 64 + srow) * DI + k0 + g * 8;

    f32x4 acc[4][4];
    acc_zero4(acc);

    // preload step 0
    float4 A00 = *(const float4*)(ap0), A01 = *(const float4*)(ap0 + 4);
    float4 A10 = *(const float4*)(ap1), A11 = *(const float4*)(ap1 + 4);
    float4 B00 = *(const float4*)(bp0), B01 = *(const float4*)(bp0 + 4);
    float4 B10 = *(const float4*)(bp1), B11 = *(const float4*)(bp1 + 4);

    for (int t = 0; t < 8; ++t) {
      float4 nA00, nA01, nA10, nA11, nB00, nB01, nB10, nB11;
      if (t < 7) {               // issue next-step loads early (hide under MFMA)
        const int o = (t + 1) * 32;
        nA00 = *(const float4*)(ap0 + o); nA01 = *(const float4*)(ap0 + o + 4);
        nA10 = *(const float4*)(ap1 + o); nA11 = *(const float4*)(ap1 + o + 4);
        nB00 = *(const float4*)(bp0 + o); nB01 = *(const float4*)(bp0 + o + 4);
        nB10 = *(const float4*)(bp1 + o); nB11 = *(const float4*)(bp1 + o + 4);
      }
      // stage current step (reg -> cvt -> LDS), r5h layout
      *(bf16x8*)(lds + tid * 16)         = cvt8(A00, A01);
      *(bf16x8*)(lds + 4096 + tid * 16)  = cvt8(A10, A11);
      *(bf16x8*)(lds + 8192 + tid * 16)  = cvt8(B00, B01);
      *(bf16x8*)(lds + 12288 + tid * 16) = cvt8(B10, B11);
      __syncthreads();
      {
        const char* Ab = lds + wr * 4096;
        const char* Bb = lds + 8192 + wc * 4096;
        bf16x8 a[4], bq[4];
#pragma unroll
        for (int fm = 0; fm < 4; ++fm) a[fm] = *(const bf16x8*)(Ab + fm * 1024 + aoff);
#pragma unroll
        for (int fn = 0; fn < 4; ++fn) bq[fn] = *(const bf16x8*)(Bb + fn * 1024 + aoff);
#pragma unroll
        for (int fm = 0; fm < 4; ++fm)
#pragma unroll
          for (int fn = 0; fn < 4; ++fn)
            acc[fm][fn] = __builtin_amdgcn_mfma_f32_16x16x32_bf16(
                a[fm], bq[fn], acc[fm][fn], 0, 0, 0);
      }
      __syncthreads();
      A00 = nA00; A01 = nA01; A10 = nA10; A11 = nA11;
      B00 = nB00; B01 = nB01; B10 = nB10; B11 = nB11;
    }

    float* MPs = MTp + (size_t)s * (1024 * 1024);
    const int r4 = (lane >> 4) * 4, cn = lane & 15;
#pragma unroll
    for (int fm = 0; fm < 4; ++fm)
#pragma unroll
      for (int fn = 0; fn < 4; ++fn) {
        const int rowb = m0 + wr * 64 + fm * 16 + r4;
        const int col  = n0 + wc * 64 + fn * 16 + cn;
#pragma unroll
        for (int rr = 0; rr < 4; ++rr)
          MPs[(size_t)(rowb + rr) * 1024 + col] = acc[fm][fn][rr];
      }
  } else if (bid < 4352) {
    // ---- x cast ----
    const size_t i = ((size_t)(bid - 256) * 256 + tid) * 8;
    const float4 a = *(const float4*)(x + i);
    const float4 c = *(const float4*)(x + i + 4);
    *(bf16x8*)(xb + i) = cvt8(a, c);
  } else if (bid < 5376) {
    // ---- Wv transpose-cast: 32x32 tile ----
    float (*t)[33] = (float (*)[33])lds;
    const int tt = bid - 4352;
    const int c0 = (tt & 31) * 32, k0 = (tt >> 5) * 32;
    const int tx = tid & 31, ty = tid >> 5;   // 32 x 8
#pragma unroll
    for (int i = 0; i < 4; ++i)
      t[ty + 8 * i][tx] = Wv[(size_t)(k0 + ty + 8 * i) * DI + c0 + tx];
    __syncthreads();
#pragma unroll
    for (int i = 0; i < 4; ++i)
      WTv[(size_t)(c0 + ty + 8 * i) * DI + k0 + tx] = (bf16)t[tx][ty + 8 * i];
  } else {
    // ---- RS zero: 8192 f32 = 32 f32/thread ----
    float4 z = {0.f, 0.f, 0.f, 0.f};
#pragma unroll
    for (int i = 0; i < 8; ++i)
      *(float4*)(RS + (size_t)tid * 32 + i * 4) = z;
  }
}

// ---- mtred: reduce 4 MTp planes (f32) -> MT (bf16), 512 blocks -------------
__global__ __launch_bounds__(256) void k_mtred(const float* __restrict__ MTp,
                                               bf16* __restrict__ MT) {
  const size_t i = ((size_t)blockIdx.x * 256 + threadIdx.x) * 8;
  float4 a = *(const float4*)(MTp + i);
  float4 b = *(const float4*)(MTp + i + 4);
#pragma unroll
  for (int s = 1; s < 4; ++s) {
    const float* p = MTp + (size_t)s * (1024 * 1024) + i;
    const float4 c = *(const float4*)p;
    const float4 d = *(const float4*)(p + 4);
    a.x += c.x; a.y += c.y; a.z += c.z; a.w += c.w;
    b.x += d.x; b.y += d.y; b.z += d.z; b.w += d.w;
  }
  *(bf16x8*)(MT + i) = cvt8(a, b);
}

// ------- T|V fused: 256x256 4-phase counted-vmcnt + XOR bank-swizzle --------
// r20 verified: both-sides XOR swizzle (linear gload_lds dest +
// inverse-swizzled global source kq^(srow8&7) + swizzled read ^(l15&7)<<4)
// -> bank conflicts 9.4M -> 0. tv ~50us; total benefit also flows to qk via
// contiguous 256-row T slabs per XCD (better qk A-panel L2 locality).
__global__ __launch_bounds__(512, 2) void k_tv(const bf16* __restrict__ X,
                                               const bf16* __restrict__ MT,
                                               const bf16* __restrict__ WTv,
                                               bf16* __restrict__ T,
                                               bf16* __restrict__ VT) {
  __shared__ __align__(16) char lds[131072];
  const int bid  = blockIdx.x;
  // XCD-aware bijective swizzle: 256 = 8 * 32
  const int wgid = (bid & 7) * 32 + (bid >> 3);
  const int m0 = (wgid >> 3) * 256;
  const int n0 = (wgid & 7) * 256;

  const bf16* Ag = X + (size_t)m0 * 1024;
  const bf16* Bg = (n0 < 1024) ? MT + (size_t)n0 * 1024
                               : WTv + (size_t)(n0 - 1024) * 1024;

  const int tid = threadIdx.x, lane = tid & 63, w = tid >> 6;
  const int wr = w >> 2, wcn = w & 3;
  const int l15 = lane & 15, lg = lane >> 4;
  const int srow8 = tid >> 3, kq = tid & 7;
  const int kqs = kq ^ (srow8 & 7);        // pre-swizzled source col16
  const int swz = (l15 & 7) << 4;          // read-side XOR (bits 4-6)

  // fragment lane offsets in the [256 rows][128B] buffers (pre-XOR)
  const int aBase = wr * 16384 + l15 * 128 + lg * 16;   // A: wr*128 rows
  const int bBase = wcn * 8192 + l15 * 128 + lg * 16;   // B: wcn*64 rows

  // q: 0=A-lo 1=A-hi 2=B-lo 3=B-hi ; dest = uniform + tid*16 (gload_lds rule)
  auto STGH = [&](int t, int q) {
    char* dst = lds + (t & 1) * 65536 + ((q & 2) ? 32768 : 0)
                + ((q & 1) ? 16384 : 0);
    const bf16* src = (q & 2) ? Bg : Ag;
    const int rb = (q & 1) ? 128 : 0;
#pragma unroll
    for (int j = 0; j < 2; ++j)
      gload_lds16(src + (size_t)(rb + j * 64 + srow8) * 1024 + t * 64 + kqs * 8,
                  dst + j * 8192 + tid * 16);
  };

  f32x4 acc[8][4];
#pragma unroll
  for (int i = 0; i < 8; ++i)
#pragma unroll
    for (int j = 0; j < 4; ++j)
      acc[i][j] = (f32x4){0.f, 0.f, 0.f, 0.f};

  // prologue: t0 all 4 halves; t1 Alo, Ahi, Blo (Bhi staged at t0-p0)
  STGH(0, 0); STGH(0, 1); STGH(0, 2); STGH(0, 3);
  STGH(1, 0); STGH(1, 1); STGH(1, 2);

  for (int t = 0; t < 16; ++t) {
    if (t < 15) { VMW6; } else { VMW0; }
    BARX;                                   // buffer t&1 resident (all waves)
    const char* Ab = lds + (t & 1) * 65536;
    const char* Bb = Ab + 32768;
    bf16x8 a[8], b[4], b2[4];

    // ---- p0: fm0-3 x fn0-1 ----
#pragma unroll
    for (int fm = 0; fm < 4; ++fm)
#pragma unroll
      for (int kk = 0; kk < 2; ++kk)
        a[fm * 2 + kk] = *(const bf16x8*)(Ab + ((aBase + fm * 2048 + kk * 64) ^ swz));
#pragma unroll
    for (int fn = 0; fn < 2; ++fn)
#pragma unroll
      for (int kk = 0; kk < 2; ++kk)
        b[fn * 2 + kk] = *(const bf16x8*)(Bb + ((bBase + fn * 2048 + kk * 64) ^ swz));
    if (t + 1 < 16) STGH(t + 1, 3);
    BARX;
    __builtin_amdgcn_s_setprio(1);
#pragma unroll
    for (int fm = 0; fm < 4; ++fm)
#pragma unroll
      for (int fn = 0; fn < 2; ++fn)
#pragma unroll
        for (int kk = 0; kk < 2; ++kk)
          acc[fm][fn] = __builtin_amdgcn_mfma_f32_16x16x32_bf16(
              a[fm * 2 + kk], b[fn * 2 + kk], acc[fm][fn], 0, 0, 0);
    __builtin_amdgcn_s_setprio(0);
    BARX;

    // ---- p1: fm0-3 x fn2-3 (reuse a) ----
#pragma unroll
    for (int fn = 0; fn < 2; ++fn)
#pragma unroll
      for (int kk = 0; kk < 2; ++kk)
        b2[fn * 2 + kk] = *(const bf16x8*)(Bb + ((bBase + 4096 + fn * 2048 + kk * 64) ^ swz));
    BARX;
    __builtin_amdgcn_s_setprio(1);
#pragma unroll
    for (int fm = 0; fm < 4; ++fm)
#pragma unroll
      for (int fn = 0; fn < 2; ++fn)
#pragma unroll
        for (int kk = 0; kk < 2; ++kk)
          acc[fm][2 + fn] = __builtin_amdgcn_mfma_f32_16x16x32_bf16(
              a[fm * 2 + kk], b2[fn * 2 + kk], acc[fm][2 + fn], 0, 0, 0);
    __builtin_amdgcn_s_setprio(0);
    BARX;

    // ---- p2: fm4-7 x fn0-1 (read a2 into a[], reuse b) ----
#pragma unroll
    for (int fm = 0; fm < 4; ++fm)
#pragma unroll
      for (int kk = 0; kk < 2; ++kk)
        a[fm * 2 + kk] = *(const bf16x8*)(Ab + ((aBase + 8192 + fm * 2048 + kk * 64) ^ swz));
    if (t + 2 < 16) STGH(t + 2, 2);
    BARX;
    __builtin_amdgcn_s_setprio(1);
#pragma unroll
    for (int fm = 0; fm < 4; ++fm)
#pragma unroll
      for (int fn = 0; fn < 2; ++fn)
#pragma unroll
        for (int kk = 0; kk < 2; ++kk)
          acc[4 + fm][fn] = __builtin_amdgcn_mfma_f32_16x16x32_bf16(
              a[fm * 2 + kk], b[fn * 2 + kk], acc[4 + fm][fn], 0, 0, 0);
    __builtin_amdgcn_s_setprio(0);
    BARX;

    // ---- p3: fm4-7 x fn2-3 (reuse a2, b2) ----
    if (t + 2 < 16) { STGH(t + 2, 0); STGH(t + 2, 1); }
    BARX;
    __builtin_amdgcn_s_setprio(1);
#pragma unroll
    for (int fm = 0; fm < 4; ++fm)
#pragma unroll
      for (int fn = 0; fn < 2; ++fn)
#pragma unroll
        for (int kk = 0; kk < 2; ++kk)
          acc[4 + fm][2 + fn] = __builtin_amdgcn_mfma_f32_16x16x32_bf16(
              a[fm * 2 + kk], b2[fn * 2 + kk], acc[4 + fm][2 + fn], 0, 0, 0);
    __builtin_amdgcn_s_setprio(0);
    BARX;
  }

  // ---- epilogue (r4/r16-verified mapping) ----
  const int r4 = (lane >> 4) * 4;
  const int cn = lane & 15;
  if (n0 < 1024) {
#pragma unroll
    for (int fm = 0; fm < 8; ++fm) {
      const int row = m0 + wr * 128 + fm * 16 + r4;
#pragma unroll
      for (int fn = 0; fn < 4; ++fn) {
        const int n = n0 + wcn * 64 + fn * 16 + cn;
        const size_t base = (size_t)row * 1024 + n;
#pragma unroll
        for (int r = 0; r < 4; ++r)
          T[base + (size_t)r * 1024] = (bf16)acc[fm][fn][r];
      }
    }
  } else {
    const int b_ = m0 >> 11;
    const int sb = (m0 & 2047) + wr * 128 + r4;
    // fn outer / fm inner: each VT line completes in consecutive stores
#pragma unroll
    for (int fn = 0; fn < 4; ++fn) {
      const int d = (n0 - 1024) + wcn * 64 + fn * 16 + cn;
      bf16* vp = VT + ((size_t)b_ * DOUT + d) * SS;
#pragma unroll
      for (int fm = 0; fm < 8; ++fm) {
        const int s0 = sb + fm * 16;
        ushort4 pk;
        pk.x = __builtin_bit_cast(unsigned short, (bf16)acc[fm][fn][0]);
        pk.y = __builtin_bit_cast(unsigned short, (bf16)acc[fm][fn][1]);
        pk.z = __builtin_bit_cast(unsigned short, (bf16)acc[fm][fn][2]);
        pk.w = __builtin_bit_cast(unsigned short, (bf16)acc[fm][fn][3]);
        *(ushort4*)(vp + s0) = pk;
      }
    }
  }
}

// ---- scores = T.X^T, fused exp: causal mask + exp(s*scale) + row-sum -------
// Hybrid tail-balanced work-list (576 blocks = per-XCD {64 full r5h + 8 thin
// r5q halves of 4 tiles}).
__global__ __launch_bounds__(256, 3) void k_gemm_qk(const bf16* __restrict__ T,
                                                    const bf16* __restrict__ XB,
                                                    bf16* __restrict__ E,
                                                    float* __restrict__ RS) {
  __shared__ __align__(16) char lds[49152];
  const int c  = blockIdx.x & 7;          // XCD
  const int li = blockIdx.x >> 3;         // 0..71 within XCD chunk
  const bool full = (li < 64);
  const int gt = full ? (c * 68 + li) : (c * 68 + 64 + ((li - 64) >> 1));
  const int nh = full ? 0 : ((li - 64) & 1);

  const int b = gt / 136;
  int r = gt % 136;
  int i = 0;
  for (;;) { const int cnt = i + 1; if (r < cnt) break; r -= cnt; ++i; }
  const int m0 = i * 128;

  bf16* Eb = E + (size_t)b * SS * SS;
  float* RSb = RS + (size_t)b * SS;
  const float scale = 0.03125f;  // 1/sqrt(1024)
  const int lane = threadIdx.x & 63, wid = threadIdx.x >> 6;
  const int wr = wid >> 1, wc = wid & 1;
  const int r4 = (lane >> 4) * 4, cn = lane & 15;

  float rsum[4][4];
#pragma unroll
  for (int fm = 0; fm < 4; ++fm)
#pragma unroll
    for (int rr = 0; rr < 4; ++rr) rsum[fm][rr] = 0.f;

  if (full) {
    const int n0 = r * 128;
    f32x4 acc[4][4];
    acc_zero4(acc);
    r5h_loop3(T  + ((size_t)b * SS + m0) * 1024, 1024,
              XB + ((size_t)b * SS + n0) * 1024, 1024, 32, lds, acc);
#pragma unroll
    for (int fm = 0; fm < 4; ++fm)
#pragma unroll
      for (int fn = 0; fn < 4; ++fn) {
        const int n = n0 + wc * 64 + fn * 16 + cn;
        const int rowb = m0 + wr * 64 + fm * 16 + r4;
        const size_t bofs = (size_t)rowb * SS + n;
#pragma unroll
        for (int rr = 0; rr < 4; ++rr) {
          const float e = (n <= rowb + rr) ? __expf(acc[fm][fn][rr] * scale) : 0.f;
          Eb[bofs + (size_t)rr * SS] = (bf16)e;
          rsum[fm][rr] += e;
        }
      }
  } else {
    const int n0 = r * 128 + nh * 64;
    f32x4 acc[4][2];
#pragma unroll
    for (int ii = 0; ii < 4; ++ii)
#pragma unroll
      for (int jj = 0; jj < 2; ++jj)
        acc[ii][jj] = (f32x4){0.f, 0.f, 0.f, 0.f};
    r5q_loop3(T  + ((size_t)b * SS + m0) * 1024, 1024,
              XB + ((size_t)b * SS + n0) * 1024, 1024, 32, lds, acc);
#pragma unroll
    for (int fm = 0; fm < 4; ++fm)
#pragma unroll
      for (int fn = 0; fn < 2; ++fn) {
        const int n = n0 + wc * 32 + fn * 16 + cn;
        const int rowb = m0 + wr * 64 + fm * 16 + r4;
        const size_t bofs = (size_t)rowb * SS + n;
#pragma unroll
        for (int rr = 0; rr < 4; ++rr) {
          const float e = (n <= rowb + rr) ? __expf(acc[fm][fn][rr] * scale) : 0.f;
          Eb[bofs + (size_t)rr * SS] = (bf16)e;
          rsum[fm][rr] += e;
        }
      }
  }

  // reduce over the 16 cn-lanes (same row group: lane>>4 invariant under xor<16)
#pragma unroll
  for (int fm = 0; fm < 4; ++fm)
#pragma unroll
    for (int rr = 0; rr < 4; ++rr) {
      float s = rsum[fm][rr];
      s += __shfl_xor(s, 1);
      s += __shfl_xor(s, 2);
      s += __shfl_xor(s, 4);
      s += __shfl_xor(s, 8);
      if (cn == 0)
        atomicAdd(&RSb[m0 + wr * 64 + fm * 16 + r4 + rr], s);
    }
}

// ---------------- PV: r5h3, anti-correlated balance (512 blocks) ------------
// Consumes unnormalized E; divides by RS[row] in epilogue.
__global__ __launch_bounds__(256, 3) void k_gemm_pv(const bf16* __restrict__ P,
                                                    const bf16* __restrict__ VT,
                                                    const float* __restrict__ RS,
                                                    float* __restrict__ Out) {
  __shared__ __align__(16) char lds[49152];
  const int wfl = blockIdx.x;
  const int h = wfl >> 8;
  const int r = wfl & 255;
  const int b = r >> 6;
  const int t = r & 63;
  const int ip = t >> 3;
  const int j = t & 7;
  const int i = h ? (15 - ip) : ip;
  const int m0 = i * 128, n0 = j * 128;
  const int nt = 4 * (i + 1);     // s-tiles [0, (i+1)*128)

  f32x4 acc[4][4];
  acc_zero4(acc);
  r5h_loop3(P  + (size_t)b * SS * SS   + (size_t)m0 * SS, SS,
            VT + (size_t)b * DOUT * SS + (size_t)n0 * SS, SS,
            nt, lds, acc);

  float* Ob = Out + (size_t)b * SS * DOUT;
  const float* RSb = RS + (size_t)b * SS;
  const int lane = threadIdx.x & 63, wid = threadIdx.x >> 6;
  const int wr = wid >> 1, wc = wid & 1;
  const int r4 = (lane >> 4) * 4, cn = lane & 15;
#pragma unroll
  for (int fm = 0; fm < 4; ++fm) {
    const int rowb = m0 + wr * 64 + fm * 16 + r4;
    const float4 rs4 = *(const float4*)(RSb + rowb);
    float inv[4];
    inv[0] = 1.0f / rs4.x; inv[1] = 1.0f / rs4.y;
    inv[2] = 1.0f / rs4.z; inv[3] = 1.0f / rs4.w;
#pragma unroll
    for (int fn = 0; fn < 4; ++fn) {
      const int n = n0 + wc * 64 + fn * 16 + cn;
      const size_t bofs = (size_t)rowb * DOUT + n;
#pragma unroll
      for (int rr = 0; rr < 4; ++rr)
        Ob[bofs + (size_t)rr * DOUT] = acc[fm][fn][rr] * inv[rr];
    }
  }
}

// ---------------- launch ----------------
extern "C" void kernel_launch(void* const* d_in, const int* in_sizes, int n_in,
                              void* d_out, int out_size, void* d_ws, size_t ws_size,
                              hipStream_t stream) {
  const float* x  = (const float*)d_in[0];
  const float* Wq = (const float*)d_in[1];
  const float* Wk = (const float*)d_in[2];
  const float* Wv = (const float*)d_in[3];
  float* out = (float*)d_out;
  char* ws = (char*)d_ws;

  bf16*  T   = (bf16*)(ws);                        // 16 MB [8192][1024]  X*M
  bf16*  VT  = (bf16*)(ws + ((size_t)16 << 20));   // 16 MB [4][1024][2048]
  bf16*  E   = (bf16*)(ws + ((size_t)32 << 20));   // 32 MB unnorm exp scores
  float* MTp = (float*)(ws + ((size_t)32 << 20));  // 16 MB (aliases E; dead before qk)
  bf16*  XB  = (bf16*)(ws + ((size_t)64 << 20));   // 16 MB (live through qk!)
  bf16*  WTv = (bf16*)(ws + ((size_t)80 << 20));   //  2 MB transposed bf16 Wv
  bf16*  MT  = (bf16*)(ws + ((size_t)82 << 20));   //  2 MB M^T = Wk.Wq^T (bf16)
  float* RS  = (float*)(ws + ((size_t)84 << 20));  // 32 KB row sums [4][2048]

  k_prep<<<5377, 256, 0, stream>>>(x, XB, Wq, Wk, Wv, WTv, MTp, RS);
  k_mtred<<<512, 256, 0, stream>>>(MTp, MT);
  k_tv<<<256, 512, 0, stream>>>(XB, MT, WTv, T, VT);
  k_gemm_qk<<<576, 256, 0, stream>>>(T, XB, E, RS);
  k_gemm_pv<<<512, 256, 0, stream>>>(E, VT, RS, out);
}